// Round 9
// baseline (453.777 us; speedup 1.0000x reference)
//
#include <hip/hip_runtime.h>
#include <math.h>

// Problem constants (fixed by reference)
#define NN   10000
#define EE   160000
#define GG   128
#define HIDK 25
#define DOUT 32
#define EPSBN 1e-5f

// ---------------- workspace layout (float offsets) ----------------
// zeroed region (one hipMemsetAsync):
#define OFF_CUR   0          // NN ints (scatter cursors), pad 10016
#define OFF_GSUM  10016      // G*32 = 4096
#define OFF_DEGC  14112      // NN ints, pad 10016
#define ZERO_FLOATS 24128
// non-zeroed:
#define OFF_MOP   24128      // 64*12
#define OFF_W1F0  24896      // 80
#define OFF_B1F0  24976      // 32
#define OFF_W1F1  25008      // 80
#define OFF_B1F1  25088      // 32
#define OFF_ROW   25120      // NN+1 ints, pad 10016
#define OFF_SRC   35136      // E ints
#define OFF_EID   195136     // E ints
#define OFF_WBT0  355136     // 32*512  = 16384  (W^T[o][K], layer0)
#define OFF_WBT1  371520     // 32*1024 = 32768  (W^T[o][K], layer1)
#define OFF_H     404288     // E*32 = 5,120,000 (h in CSR-slot order, per layer)
#define OFF_S     5524288    // N*1024 = 10,240,000 (S, shared by both layers)
#define OFF_X1    15764288   // N*32
#define TOTAL_FLOATS 16084288 // ~64.3 MB of d_ws

__device__ inline float wave_red(float v) {
    for (int off = 32; off; off >>= 1) v += __shfl_down(v, off);
    return v;
}

// ---- moments partials (64 blocks, atomic-free) + in-degree atomics, one pass
__global__ void k_momdeg(const float* __restrict__ ea, const int* __restrict__ ei,
                         float* __restrict__ mop, int* __restrict__ degc) {
    __shared__ float ls[4][9];
    float s[9];
#pragma unroll
    for (int j = 0; j < 9; j++) s[j] = 0.f;
    int t = threadIdx.x;
    for (int e = blockIdx.x * 256 + t; e < EE; e += 64 * 256) {
        float a0 = ea[3 * e], a1 = ea[3 * e + 1], a2 = ea[3 * e + 2];
        s[0] += a0; s[1] += a1; s[2] += a2;
        s[3] += a0 * a0; s[4] += a0 * a1; s[5] += a0 * a2;
        s[6] += a1 * a1; s[7] += a1 * a2; s[8] += a2 * a2;
        atomicAdd(degc + ei[EE + e], 1);
    }
    int w = t >> 6, lane = t & 63;
#pragma unroll
    for (int j = 0; j < 9; j++) {
        float r = wave_red(s[j]);
        if (lane == 0) ls[w][j] = r;
    }
    __syncthreads();
    if (t < 9) mop[blockIdx.x * 12 + t] = ls[0][t] + ls[1][t] + ls[2][t] + ls[3][t];
}

// ---- single-block exclusive scan of degc -> row_start[NN+1]
__global__ void k_scan(const int* __restrict__ degc, int* __restrict__ row_start) {
    __shared__ int p[256];
    int t = threadIdx.x;
    const int CHUNK = 40;                 // 250*40 == 10000 exactly
    int base = t * CHUNK;
    int sum = 0;
    if (t < 250) {
        for (int i = 0; i < CHUNK; i++) sum += degc[base + i];
    }
    p[t] = sum;
    __syncthreads();
    for (int off = 1; off < 256; off <<= 1) {
        int v = (t >= off) ? p[t - off] : 0;
        __syncthreads();
        p[t] += v;
        __syncthreads();
    }
    int excl = p[t] - sum;
    if (t < 250) {
        int run = excl;
        for (int i = 0; i < CHUNK; i++) {
            row_start[base + i] = run;
            run += degc[base + i];
        }
    }
    if (t == 0) row_start[NN] = EE;
}

// ---- scatter edges into CSR slots
__global__ void k_scatter(const int* __restrict__ ei, const int* __restrict__ row_start,
                          int* __restrict__ cur, int* __restrict__ csr_src,
                          int* __restrict__ csr_eid) {
    int e = blockIdx.x * blockDim.x + threadIdx.x;
    if (e >= EE) return;
    int d = ei[EE + e];
    int pos = atomicAdd(cur + d, 1);
    int idx = row_start[d] + pos;
    csr_src[idx] = ei[e];
    csr_eid[idx] = e;
}

// ---- merged prep: blocks 0..191 pack W^T for both layers; block 192 folds BN.
// W^T[o][K] layout matches k_sedge's S layout: K = lane*KPL + j,
//   lane = (kh,il): il = lane & (DIN-1), kh = lane / DIN, k = kh*KPL + j.
// k<25 -> w2 ; k==25 -> b2 ; k>25 -> 0.
__global__ void k_prep(const float* __restrict__ mop,
                       const float* __restrict__ w1_0, const float* __restrict__ b1_0,
                       const float* __restrict__ g_0, const float* __restrict__ be_0,
                       const float* __restrict__ w1_1, const float* __restrict__ b1_1,
                       const float* __restrict__ g_1, const float* __restrict__ be_1,
                       const float* __restrict__ w2_0, const float* __restrict__ b2_0,
                       const float* __restrict__ w2_1, const float* __restrict__ b2_1,
                       float* __restrict__ w1f0, float* __restrict__ b1f0,
                       float* __restrict__ w1f1, float* __restrict__ b1f1,
                       float* __restrict__ wbt0, float* __restrict__ wbt1) {
    int b = blockIdx.x, t = threadIdx.x;
    if (b < 192) {
        int idx = b * 256 + t;
        if (idx < 32 * 512) {                       // layer0: KT=512, DIN=16, KPL=8
            int o = idx >> 9, K = idx & 511;
            int lane = K >> 3, j = K & 7;
            int kh = lane >> 4, il = lane & 15;
            int k = kh * 8 + j;
            float v = 0.f;
            if (k < HIDK) v = w2_0[(k * 16 + il) * DOUT + o];
            else if (k == HIDK) v = b2_0[il * DOUT + o];
            wbt0[idx] = v;
        } else {                                    // layer1: KT=1024, DIN=32, KPL=16
            int idx2 = idx - 32 * 512;
            int o = idx2 >> 10, K = idx2 & 1023;
            int lane = K >> 4, j = K & 15;
            int kh = lane >> 5, il = lane & 31;
            int k = kh * 16 + j;
            float v = 0.f;
            if (k < HIDK) v = w2_1[(k * 32 + il) * DOUT + o];
            else if (k == HIDK) v = b2_1[il * DOUT + o];
            wbt1[idx2] = v;
        }
        return;
    }
    // ---- block 192: fold BN for both layers
    __shared__ float mo[9];
    if (t < 9) {
        float s = 0.f;
        for (int bb = 0; bb < 64; bb++) s += mop[bb * 12 + t];
        mo[t] = s;
    }
    __syncthreads();
    int grp = t >> 5, j = t & 31;
    if (t >= 64 || j >= HIDK) return;
    const float* w1 = grp ? w1_1 : w1_0;
    const float* b1 = grp ? b1_1 : b1_0;
    const float* g  = grp ? g_1  : g_0;
    const float* be = grp ? be_1 : be_0;
    float* w1f = grp ? w1f1 : w1f0;
    float* b1f = grp ? b1f1 : b1f0;
    const float inv = 1.0f / (float)EE;
    float m0 = mo[0] * inv, m1 = mo[1] * inv, m2 = mo[2] * inv;
    float c00 = mo[3] * inv - m0 * m0, c01 = mo[4] * inv - m0 * m1, c02 = mo[5] * inv - m0 * m2;
    float c11 = mo[6] * inv - m1 * m1, c12 = mo[7] * inv - m1 * m2, c22 = mo[8] * inv - m2 * m2;
    float w0 = w1[j], wa = w1[25 + j], wb = w1[50 + j];
    float mean = m0 * w0 + m1 * wa + m2 * wb + b1[j];
    float var = w0 * w0 * c00 + wa * wa * c11 + wb * wb * c22
              + 2.f * (w0 * wa * c01 + w0 * wb * c02 + wa * wb * c12);
    float sc = g[j] * rsqrtf(var + EPSBN);
    w1f[j] = w0 * sc; w1f[25 + j] = wa * sc; w1f[50 + j] = wb * sc;
    b1f[j] = (b1[j] - mean) * sc + be[j];
}

// ---- h in CSR-slot order: hcsr[slot][k] = relu(ea[eid]@w1f+b1f)[k]; k=25 -> 1; pad -> 0
__global__ void k_h(const float* __restrict__ ea, const int* __restrict__ csr_eid,
                    const float* __restrict__ w1f, const float* __restrict__ b1f,
                    float* __restrict__ hcsr) {
    int t = threadIdx.x;
    int slot = blockIdx.x * 8 + (t >> 5);   // 20000 blocks exactly
    int k = t & 31;
    int e = csr_eid[slot];
    float v = 0.f;
    if (k < HIDK) {
        float a0 = ea[3 * e], a1 = ea[3 * e + 1], a2 = ea[3 * e + 2];
        v = a0 * w1f[k] + a1 * w1f[25 + k] + a2 * w1f[50 + k] + b1f[k];
        v = v > 0.f ? v : 0.f;
    } else if (k == HIDK) {
        v = 1.0f;
    }
    hcsr[(size_t)slot * 32 + k] = v;
}

// ---- Phase A: S[n][K] = sum_{edges of n} h[slot][k] * x[src, i]
// One wave per node, 4-edge unroll, S in registers, no LDS/barriers.
// Lane layout: il = lane & (DIN-1), kh = lane/DIN owns k = kh*KPL + j.
// S stored lane-major: S[n*KT + lane*KPL + j] -> KPL/4 coalesced b128 stores.
template <int DIN, int KPL, int KT>
__global__ void k_sedge(const int* __restrict__ row_start, const int* __restrict__ csr_src,
                        const float* __restrict__ hcsr, const float* __restrict__ xin,
                        float* __restrict__ S) {
    int t = threadIdx.x;
    int w = t >> 6, lane = t & 63;
    int n = blockIdx.x * 4 + w;            // grid 2500
    int start = row_start[n], end = row_start[n + 1];
    int il = lane & (DIN - 1);
    int kh = lane / DIN;
    float s[KPL];
#pragma unroll
    for (int j = 0; j < KPL; j++) s[j] = 0.f;

    for (int p = start; p < end; p += 4) {
        int e1 = end - 1;
        int q0 = p;
        int q1 = (p + 1 < end) ? p + 1 : e1;
        int q2 = (p + 2 < end) ? p + 2 : e1;
        int q3 = (p + 3 < end) ? p + 3 : e1;
        bool v1 = p + 1 < end, v2 = p + 2 < end, v3 = p + 3 < end;
        int s0 = csr_src[q0], s1 = csr_src[q1], s2 = csr_src[q2], s3 = csr_src[q3];
        const float4* h0 = (const float4*)(hcsr + (size_t)q0 * 32 + kh * KPL);
        const float4* h1 = (const float4*)(hcsr + (size_t)q1 * 32 + kh * KPL);
        const float4* h2 = (const float4*)(hcsr + (size_t)q2 * 32 + kh * KPL);
        const float4* h3 = (const float4*)(hcsr + (size_t)q3 * 32 + kh * KPL);
        float4 H0[KPL / 4], H1[KPL / 4], H2[KPL / 4], H3[KPL / 4];
#pragma unroll
        for (int j4 = 0; j4 < KPL / 4; j4++) {
            H0[j4] = h0[j4]; H1[j4] = h1[j4]; H2[j4] = h2[j4]; H3[j4] = h3[j4];
        }
        float x0 = xin[s0 * DIN + il];
        float x1 = v1 ? xin[s1 * DIN + il] : 0.f;
        float x2 = v2 ? xin[s2 * DIN + il] : 0.f;
        float x3 = v3 ? xin[s3 * DIN + il] : 0.f;
#pragma unroll
        for (int j4 = 0; j4 < KPL / 4; j4++) {
            s[j4 * 4 + 0] += H0[j4].x * x0; s[j4 * 4 + 1] += H0[j4].y * x0;
            s[j4 * 4 + 2] += H0[j4].z * x0; s[j4 * 4 + 3] += H0[j4].w * x0;
        }
#pragma unroll
        for (int j4 = 0; j4 < KPL / 4; j4++) {
            s[j4 * 4 + 0] += H1[j4].x * x1; s[j4 * 4 + 1] += H1[j4].y * x1;
            s[j4 * 4 + 2] += H1[j4].z * x1; s[j4 * 4 + 3] += H1[j4].w * x1;
        }
#pragma unroll
        for (int j4 = 0; j4 < KPL / 4; j4++) {
            s[j4 * 4 + 0] += H2[j4].x * x2; s[j4 * 4 + 1] += H2[j4].y * x2;
            s[j4 * 4 + 2] += H2[j4].z * x2; s[j4 * 4 + 3] += H2[j4].w * x2;
        }
#pragma unroll
        for (int j4 = 0; j4 < KPL / 4; j4++) {
            s[j4 * 4 + 0] += H3[j4].x * x3; s[j4 * 4 + 1] += H3[j4].y * x3;
            s[j4 * 4 + 2] += H3[j4].z * x3; s[j4 * 4 + 3] += H3[j4].w * x3;
        }
    }
    float4* Sp = (float4*)(S + (size_t)n * KT + lane * KPL);
#pragma unroll
    for (int j4 = 0; j4 < KPL / 4; j4++) {
        float4 v; v.x = s[j4 * 4]; v.y = s[j4 * 4 + 1]; v.z = s[j4 * 4 + 2]; v.w = s[j4 * 4 + 3];
        Sp[j4] = v;
    }
}

// ---- Phase B: node-blocked GEMM out[n][o] = S[n][:] . W^T[o][:], + epilogue.
// 32 nodes/block, thread = 2n x 2o register tile; A shared by 16 o-threads
// (L1 broadcast), W rows shared by 16 n-threads (L1/L2). No LDS, no barriers.
// FINAL: atomicAdd into gsum (global mean pool); else store xout.
template <int DIN, int KT, bool FINAL>
__global__ void k_gemm(const float* __restrict__ S, const float* __restrict__ WBt,
                       const int* __restrict__ row_start, const float* __restrict__ xin,
                       const float* __restrict__ wr, const float* __restrict__ bc,
                       const int* __restrict__ batch, float* __restrict__ xout,
                       float* __restrict__ gsum) {
    int t = threadIdx.x;
    int ng = t >> 4, og = t & 15;
    int n0 = blockIdx.x * 32 + ng * 2;     // grid 313 -> up to 10016, guarded
    int n1 = n0 + 1;
    int o0 = og * 2, o1 = o0 + 1;
    bool g0 = n0 < NN, g1 = n1 < NN;
    const float4* A0 = (const float4*)(S + (size_t)(g0 ? n0 : 0) * KT);
    const float4* A1 = (const float4*)(S + (size_t)(g1 ? n1 : 0) * KT);
    const float4* W0 = (const float4*)(WBt + (size_t)o0 * KT);
    const float4* W1 = (const float4*)(WBt + (size_t)o1 * KT);
    float a00 = 0.f, a01 = 0.f, a10 = 0.f, a11 = 0.f;
#pragma unroll 8
    for (int K4 = 0; K4 < KT / 4; K4++) {
        float4 av0 = A0[K4], av1 = A1[K4];
        float4 wv0 = W0[K4], wv1 = W1[K4];
        a00 += av0.x * wv0.x + av0.y * wv0.y + av0.z * wv0.z + av0.w * wv0.w;
        a01 += av0.x * wv1.x + av0.y * wv1.y + av0.z * wv1.z + av0.w * wv1.w;
        a10 += av1.x * wv0.x + av1.y * wv0.y + av1.z * wv0.z + av1.w * wv0.w;
        a11 += av1.x * wv1.x + av1.y * wv1.y + av1.z * wv1.z + av1.w * wv1.w;
    }
    // ---- epilogue: /deg + root transform + ELU + store/pool
#pragma unroll
    for (int c = 0; c < 2; c++) {
        int n = c ? n1 : n0;
        if (n >= NN) continue;
        float va = c ? a10 : a00;
        float vb = c ? a11 : a01;
        int cnt = row_start[n + 1] - row_start[n];
        float d = (float)cnt; if (d < 1.f) d = 1.f;
        float r0 = va / d + bc[o0];
        float r1 = vb / d + bc[o1];
        const float4* xr = (const float4*)(xin + (size_t)n * DIN);
#pragma unroll
        for (int i4 = 0; i4 < DIN / 4; i4++) {
            float4 xv = xr[i4];
            r0 += xv.x * wr[(i4 * 4 + 0) * DOUT + o0] + xv.y * wr[(i4 * 4 + 1) * DOUT + o0]
                + xv.z * wr[(i4 * 4 + 2) * DOUT + o0] + xv.w * wr[(i4 * 4 + 3) * DOUT + o0];
            r1 += xv.x * wr[(i4 * 4 + 0) * DOUT + o1] + xv.y * wr[(i4 * 4 + 1) * DOUT + o1]
                + xv.z * wr[(i4 * 4 + 2) * DOUT + o1] + xv.w * wr[(i4 * 4 + 3) * DOUT + o1];
        }
        r0 = r0 > 0.f ? r0 : expm1f(r0);
        r1 = r1 > 0.f ? r1 : expm1f(r1);
        if (FINAL) {
            int b = batch[n];
            atomicAdd(gsum + b * DOUT + o0, r0);
            atomicAdd(gsum + b * DOUT + o1, r1);
        } else {
            xout[n * DOUT + o0] = r0;
            xout[n * DOUT + o1] = r1;
        }
    }
}

// ---- final fc; per-graph node counts via binary search on SORTED batch
__global__ void k_fc(const float* __restrict__ gsum, const int* __restrict__ batch,
                     const float* __restrict__ wfc, const float* __restrict__ bfc,
                     float* __restrict__ out) {
    int g = threadIdx.x;
    if (g >= GG) return;
    int lo = 0, hi = NN;
    while (lo < hi) { int mid = (lo + hi) >> 1; if (batch[mid] < g) lo = mid + 1; else hi = mid; }
    int lb = lo;
    lo = 0; hi = NN;
    while (lo < hi) { int mid = (lo + hi) >> 1; if (batch[mid] < g + 1) lo = mid + 1; else hi = mid; }
    float c = (float)(lo - lb); if (c < 1.f) c = 1.f;
    float acc = 0.f;
#pragma unroll
    for (int o = 0; o < DOUT; o++) acc += gsum[g * DOUT + o] * wfc[o];
    out[g] = acc / c + bfc[0];
}

extern "C" void kernel_launch(void* const* d_in, const int* in_sizes, int n_in,
                              void* d_out, int out_size, void* d_ws, size_t ws_size,
                              hipStream_t stream) {
    const float* x     = (const float*)d_in[0];
    const float* ea    = (const float*)d_in[1];
    const int*   ei    = (const int*)d_in[2];
    const int*   batch = (const int*)d_in[3];
    const float* w1_0 = (const float*)d_in[4];
    const float* b1_0 = (const float*)d_in[5];
    const float* g_0  = (const float*)d_in[6];
    const float* be_0 = (const float*)d_in[7];
    const float* w2_0 = (const float*)d_in[8];
    const float* b2_0 = (const float*)d_in[9];
    const float* wr_0 = (const float*)d_in[10];
    const float* bc_0 = (const float*)d_in[11];
    const float* w1_1 = (const float*)d_in[12];
    const float* b1_1 = (const float*)d_in[13];
    const float* g_1  = (const float*)d_in[14];
    const float* be_1 = (const float*)d_in[15];
    const float* w2_1 = (const float*)d_in[16];
    const float* b2_1 = (const float*)d_in[17];
    const float* wr_1 = (const float*)d_in[18];
    const float* bc_1 = (const float*)d_in[19];
    const float* wfc  = (const float*)d_in[20];
    const float* bfc  = (const float*)d_in[21];

    float* ws    = (float*)d_ws;
    int*   cur   = (int*)(ws + OFF_CUR);
    float* gsum  = ws + OFF_GSUM;
    int*   degc  = (int*)(ws + OFF_DEGC);
    float* mop   = ws + OFF_MOP;
    float* w1f0  = ws + OFF_W1F0;
    float* b1f0  = ws + OFF_B1F0;
    float* w1f1  = ws + OFF_W1F1;
    float* b1f1  = ws + OFF_B1F1;
    int*   row   = (int*)(ws + OFF_ROW);
    int*   csrc  = (int*)(ws + OFF_SRC);
    int*   ceid  = (int*)(ws + OFF_EID);
    float* wbt0  = ws + OFF_WBT0;
    float* wbt1  = ws + OFF_WBT1;
    float* hcsr  = ws + OFF_H;
    float* Sbuf  = ws + OFF_S;
    float* x1    = ws + OFF_X1;

    hipMemsetAsync(ws, 0, (size_t)ZERO_FLOATS * sizeof(float), stream);

    k_momdeg<<<64, 256, 0, stream>>>(ea, ei, mop, degc);
    k_scan<<<1, 256, 0, stream>>>(degc, row);
    k_scatter<<<(EE + 255) / 256, 256, 0, stream>>>(ei, row, cur, csrc, ceid);
    k_prep<<<193, 256, 0, stream>>>(mop, w1_0, b1_0, g_0, be_0, w1_1, b1_1, g_1, be_1,
                                    w2_0, b2_0, w2_1, b2_1,
                                    w1f0, b1f0, w1f1, b1f1, wbt0, wbt1);

    // ---- layer 0 (din=16, K=512)
    k_h<<<EE / 8, 256, 0, stream>>>(ea, ceid, w1f0, b1f0, hcsr);
    k_sedge<16, 8, 512><<<NN / 4, 256, 0, stream>>>(row, csrc, hcsr, x, Sbuf);
    k_gemm<16, 512, false><<<(NN + 31) / 32, 256, 0, stream>>>(Sbuf, wbt0, row, x, wr_0, bc_0,
                                                               batch, x1, gsum);

    // ---- layer 1 (din=32, K=1024), pool fused into epilogue
    k_h<<<EE / 8, 256, 0, stream>>>(ea, ceid, w1f1, b1f1, hcsr);
    k_sedge<32, 16, 1024><<<NN / 4, 256, 0, stream>>>(row, csrc, hcsr, x1, Sbuf);
    k_gemm<32, 1024, true><<<(NN + 31) / 32, 256, 0, stream>>>(Sbuf, wbt1, row, x1, wr_1, bc_1,
                                                               batch, nullptr, gsum);

    // ---- fc (counts via binary search on sorted batch)
    k_fc<<<1, 128, 0, stream>>>(gsum, batch, wfc, bfc, (float*)d_out);
}

// Round 10
// 328.091 us; speedup vs baseline: 1.3831x; 1.3831x over previous
//
#include <hip/hip_runtime.h>
#include <math.h>

// Problem constants (fixed by reference)
#define NN   10000
#define EE   160000
#define GG   128
#define HIDK 25
#define DOUT 32
#define EPSBN 1e-5f

// ---------------- workspace layout (float offsets) ----------------
// zeroed region (one hipMemsetAsync):
#define OFF_CUR   0          // NN ints (scatter cursors), pad 10016
#define OFF_GSUM  10016      // G*32 = 4096
#define OFF_DEGC  14112      // NN ints, pad 10016
#define ZERO_FLOATS 24128
// non-zeroed:
#define OFF_MOP   24128      // 64*12
#define OFF_W1F0  24896      // 80
#define OFF_B1F0  24976      // 32
#define OFF_W1F1  25008      // 80
#define OFF_B1F1  25088      // 32
#define OFF_ROW   25120      // NN+1 ints, pad 10016
#define OFF_SRC   35136      // E ints
#define OFF_EID   195136     // E ints
#define OFF_WT0   355136     // 512*32  = 16384  (W[K][o], layer0)
#define OFF_WT1   371520     // 1024*32 = 32768  (W[K][o], layer1)
#define OFF_H     404288     // E*32 = 5,120,000 (h in CSR-slot order, per layer)
#define OFF_S     5524288    // N*1024 = 10,240,000 (S, shared by both layers)
#define OFF_X1    15764288   // N*32
#define TOTAL_FLOATS 16084288 // ~64.3 MB of d_ws

__device__ inline float wave_red(float v) {
    for (int off = 32; off; off >>= 1) v += __shfl_down(v, off);
    return v;
}

// ---- moments partials (64 blocks, atomic-free) + in-degree atomics, one pass
__global__ void k_momdeg(const float* __restrict__ ea, const int* __restrict__ ei,
                         float* __restrict__ mop, int* __restrict__ degc) {
    __shared__ float ls[4][9];
    float s[9];
#pragma unroll
    for (int j = 0; j < 9; j++) s[j] = 0.f;
    int t = threadIdx.x;
    for (int e = blockIdx.x * 256 + t; e < EE; e += 64 * 256) {
        float a0 = ea[3 * e], a1 = ea[3 * e + 1], a2 = ea[3 * e + 2];
        s[0] += a0; s[1] += a1; s[2] += a2;
        s[3] += a0 * a0; s[4] += a0 * a1; s[5] += a0 * a2;
        s[6] += a1 * a1; s[7] += a1 * a2; s[8] += a2 * a2;
        atomicAdd(degc + ei[EE + e], 1);
    }
    int w = t >> 6, lane = t & 63;
#pragma unroll
    for (int j = 0; j < 9; j++) {
        float r = wave_red(s[j]);
        if (lane == 0) ls[w][j] = r;
    }
    __syncthreads();
    if (t < 9) mop[blockIdx.x * 12 + t] = ls[0][t] + ls[1][t] + ls[2][t] + ls[3][t];
}

// ---- single-block exclusive scan of degc -> row_start[NN+1]
__global__ void k_scan(const int* __restrict__ degc, int* __restrict__ row_start) {
    __shared__ int p[256];
    int t = threadIdx.x;
    const int CHUNK = 40;                 // 250*40 == 10000 exactly
    int base = t * CHUNK;
    int sum = 0;
    if (t < 250) {
        for (int i = 0; i < CHUNK; i++) sum += degc[base + i];
    }
    p[t] = sum;
    __syncthreads();
    for (int off = 1; off < 256; off <<= 1) {
        int v = (t >= off) ? p[t - off] : 0;
        __syncthreads();
        p[t] += v;
        __syncthreads();
    }
    int excl = p[t] - sum;
    if (t < 250) {
        int run = excl;
        for (int i = 0; i < CHUNK; i++) {
            row_start[base + i] = run;
            run += degc[base + i];
        }
    }
    if (t == 0) row_start[NN] = EE;
}

// ---- scatter edges into CSR slots
__global__ void k_scatter(const int* __restrict__ ei, const int* __restrict__ row_start,
                          int* __restrict__ cur, int* __restrict__ csr_src,
                          int* __restrict__ csr_eid) {
    int e = blockIdx.x * blockDim.x + threadIdx.x;
    if (e >= EE) return;
    int d = ei[EE + e];
    int pos = atomicAdd(cur + d, 1);
    int idx = row_start[d] + pos;
    csr_src[idx] = ei[e];
    csr_eid[idx] = e;
}

// ---- merged prep: blocks 0..191 pack W[K][o] for both layers; block 192 folds BN.
// K is the S-layout index from k_sedge: K = lane*KPL + j, lane = (kh,il):
//   il = lane & (DIN-1), kh = lane / DIN, k = kh*KPL + j.
// k<25 -> w2[k][il][o] ; k==25 -> b2[il][o] ; k>25 -> 0.
__global__ void k_prep(const float* __restrict__ mop,
                       const float* __restrict__ w1_0, const float* __restrict__ b1_0,
                       const float* __restrict__ g_0, const float* __restrict__ be_0,
                       const float* __restrict__ w1_1, const float* __restrict__ b1_1,
                       const float* __restrict__ g_1, const float* __restrict__ be_1,
                       const float* __restrict__ w2_0, const float* __restrict__ b2_0,
                       const float* __restrict__ w2_1, const float* __restrict__ b2_1,
                       float* __restrict__ w1f0, float* __restrict__ b1f0,
                       float* __restrict__ w1f1, float* __restrict__ b1f1,
                       float* __restrict__ wt0, float* __restrict__ wt1) {
    int b = blockIdx.x, t = threadIdx.x;
    if (b < 192) {
        int idx = b * 256 + t;
        if (idx < 512 * 32) {                       // layer0: KT=512, DIN=16, KPL=8
            int K = idx >> 5, o = idx & 31;
            int lane = K >> 3, j = K & 7;
            int kh = lane >> 4, il = lane & 15;
            int k = kh * 8 + j;
            float v = 0.f;
            if (k < HIDK) v = w2_0[(k * 16 + il) * DOUT + o];
            else if (k == HIDK) v = b2_0[il * DOUT + o];
            wt0[idx] = v;
        } else {                                    // layer1: KT=1024, DIN=32, KPL=16
            int idx2 = idx - 512 * 32;
            int K = idx2 >> 5, o = idx2 & 31;
            int lane = K >> 4, j = K & 15;
            int kh = lane >> 5, il = lane & 31;
            int k = kh * 16 + j;
            float v = 0.f;
            if (k < HIDK) v = w2_1[(k * 32 + il) * DOUT + o];
            else if (k == HIDK) v = b2_1[il * DOUT + o];
            wt1[idx2] = v;
        }
        return;
    }
    // ---- block 192: fold BN for both layers
    __shared__ float mo[9];
    if (t < 9) {
        float s = 0.f;
        for (int bb = 0; bb < 64; bb++) s += mop[bb * 12 + t];
        mo[t] = s;
    }
    __syncthreads();
    int grp = t >> 5, j = t & 31;
    if (t >= 64 || j >= HIDK) return;
    const float* w1 = grp ? w1_1 : w1_0;
    const float* b1 = grp ? b1_1 : b1_0;
    const float* g  = grp ? g_1  : g_0;
    const float* be = grp ? be_1 : be_0;
    float* w1f = grp ? w1f1 : w1f0;
    float* b1f = grp ? b1f1 : b1f0;
    const float inv = 1.0f / (float)EE;
    float m0 = mo[0] * inv, m1 = mo[1] * inv, m2 = mo[2] * inv;
    float c00 = mo[3] * inv - m0 * m0, c01 = mo[4] * inv - m0 * m1, c02 = mo[5] * inv - m0 * m2;
    float c11 = mo[6] * inv - m1 * m1, c12 = mo[7] * inv - m1 * m2, c22 = mo[8] * inv - m2 * m2;
    float w0 = w1[j], wa = w1[25 + j], wb = w1[50 + j];
    float mean = m0 * w0 + m1 * wa + m2 * wb + b1[j];
    float var = w0 * w0 * c00 + wa * wa * c11 + wb * wb * c22
              + 2.f * (w0 * wa * c01 + w0 * wb * c02 + wa * wb * c12);
    float sc = g[j] * rsqrtf(var + EPSBN);
    w1f[j] = w0 * sc; w1f[25 + j] = wa * sc; w1f[50 + j] = wb * sc;
    b1f[j] = (b1[j] - mean) * sc + be[j];
}

// ---- h in CSR-slot order: hcsr[slot][k] = relu(ea[eid]@w1f+b1f)[k]; k=25 -> 1; pad -> 0
__global__ void k_h(const float* __restrict__ ea, const int* __restrict__ csr_eid,
                    const float* __restrict__ w1f, const float* __restrict__ b1f,
                    float* __restrict__ hcsr) {
    int t = threadIdx.x;
    int slot = blockIdx.x * 8 + (t >> 5);   // 20000 blocks exactly
    int k = t & 31;
    int e = csr_eid[slot];
    float v = 0.f;
    if (k < HIDK) {
        float a0 = ea[3 * e], a1 = ea[3 * e + 1], a2 = ea[3 * e + 2];
        v = a0 * w1f[k] + a1 * w1f[25 + k] + a2 * w1f[50 + k] + b1f[k];
        v = v > 0.f ? v : 0.f;
    } else if (k == HIDK) {
        v = 1.0f;
    }
    hcsr[(size_t)slot * 32 + k] = v;
}

// ---- Phase A: S[n][K] = sum_{edges of n} h[slot][k] * x[src, i]
// One wave per node, 4-edge unroll, S in registers, no LDS/barriers.
// Lane layout: il = lane & (DIN-1), kh = lane/DIN owns k = kh*KPL + j.
// S stored lane-major: S[n*KT + lane*KPL + j] -> KPL/4 coalesced b128 stores.
template <int DIN, int KPL, int KT>
__global__ void k_sedge(const int* __restrict__ row_start, const int* __restrict__ csr_src,
                        const float* __restrict__ hcsr, const float* __restrict__ xin,
                        float* __restrict__ S) {
    int t = threadIdx.x;
    int w = t >> 6, lane = t & 63;
    int n = blockIdx.x * 4 + w;            // grid 2500
    int start = row_start[n], end = row_start[n + 1];
    int il = lane & (DIN - 1);
    int kh = lane / DIN;
    float s[KPL];
#pragma unroll
    for (int j = 0; j < KPL; j++) s[j] = 0.f;

    for (int p = start; p < end; p += 4) {
        int e1 = end - 1;
        int q0 = p;
        int q1 = (p + 1 < end) ? p + 1 : e1;
        int q2 = (p + 2 < end) ? p + 2 : e1;
        int q3 = (p + 3 < end) ? p + 3 : e1;
        bool v1 = p + 1 < end, v2 = p + 2 < end, v3 = p + 3 < end;
        int s0 = csr_src[q0], s1 = csr_src[q1], s2 = csr_src[q2], s3 = csr_src[q3];
        const float4* h0 = (const float4*)(hcsr + (size_t)q0 * 32 + kh * KPL);
        const float4* h1 = (const float4*)(hcsr + (size_t)q1 * 32 + kh * KPL);
        const float4* h2 = (const float4*)(hcsr + (size_t)q2 * 32 + kh * KPL);
        const float4* h3 = (const float4*)(hcsr + (size_t)q3 * 32 + kh * KPL);
        float4 H0[KPL / 4], H1[KPL / 4], H2[KPL / 4], H3[KPL / 4];
#pragma unroll
        for (int j4 = 0; j4 < KPL / 4; j4++) {
            H0[j4] = h0[j4]; H1[j4] = h1[j4]; H2[j4] = h2[j4]; H3[j4] = h3[j4];
        }
        float x0 = xin[s0 * DIN + il];
        float x1 = v1 ? xin[s1 * DIN + il] : 0.f;
        float x2 = v2 ? xin[s2 * DIN + il] : 0.f;
        float x3 = v3 ? xin[s3 * DIN + il] : 0.f;
#pragma unroll
        for (int j4 = 0; j4 < KPL / 4; j4++) {
            s[j4 * 4 + 0] += H0[j4].x * x0; s[j4 * 4 + 1] += H0[j4].y * x0;
            s[j4 * 4 + 2] += H0[j4].z * x0; s[j4 * 4 + 3] += H0[j4].w * x0;
        }
#pragma unroll
        for (int j4 = 0; j4 < KPL / 4; j4++) {
            s[j4 * 4 + 0] += H1[j4].x * x1; s[j4 * 4 + 1] += H1[j4].y * x1;
            s[j4 * 4 + 2] += H1[j4].z * x1; s[j4 * 4 + 3] += H1[j4].w * x1;
        }
#pragma unroll
        for (int j4 = 0; j4 < KPL / 4; j4++) {
            s[j4 * 4 + 0] += H2[j4].x * x2; s[j4 * 4 + 1] += H2[j4].y * x2;
            s[j4 * 4 + 2] += H2[j4].z * x2; s[j4 * 4 + 3] += H2[j4].w * x2;
        }
#pragma unroll
        for (int j4 = 0; j4 < KPL / 4; j4++) {
            s[j4 * 4 + 0] += H3[j4].x * x3; s[j4 * 4 + 1] += H3[j4].y * x3;
            s[j4 * 4 + 2] += H3[j4].z * x3; s[j4 * 4 + 3] += H3[j4].w * x3;
        }
    }
    float4* Sp = (float4*)(S + (size_t)n * KT + lane * KPL);
#pragma unroll
    for (int j4 = 0; j4 < KPL / 4; j4++) {
        float4 v; v.x = s[j4 * 4]; v.y = s[j4 * 4 + 1]; v.z = s[j4 * 4 + 2]; v.w = s[j4 * 4 + 3];
        Sp[j4] = v;
    }
}

// ---- Phase B: node-blocked GEMM out[n][o] = S[n][:] . W[:][o], + epilogue.
// R10 reshape: 8 nodes/block (grid 1250 -> ~20 waves/CU), K split across the
// 4 waves (ks = wave id), W in [K][32] layout -> coalesced float4 loads shared
// across n-groups; S loads are half-wave broadcasts. Cross-ks reduce via LDS.
// Thread = (o4 = t&7 -> 4 o's, nl = (t>>3)&7, ks = t>>6).
// FINAL: atomicAdd into gsum (global mean pool); else store xout.
template <int DIN, int KT, bool FINAL>
__global__ void k_gemm(const float* __restrict__ S, const float* __restrict__ WT,
                       const int* __restrict__ row_start, const float* __restrict__ xin,
                       const float* __restrict__ wr, const float* __restrict__ bc,
                       const int* __restrict__ batch, float* __restrict__ xout,
                       float* __restrict__ gsum) {
    __shared__ float4 red[8][8][4];        // [nl][o4][ks], 4 KB
    int t = threadIdx.x;
    int o4 = t & 7, nl = (t >> 3) & 7, ks = t >> 6;
    int n = blockIdx.x * 8 + nl;           // grid 1250 exact
    const int KC = KT / 4;
    const float4* Sp = (const float4*)(S + (size_t)n * KT + ks * KC);
    const float* Wb = WT + (size_t)(ks * KC) * 32 + o4 * 4;
    float ax = 0.f, ay = 0.f, az = 0.f, aw = 0.f;
#pragma unroll 4
    for (int k4 = 0; k4 < KC / 4; k4++) {
        float4 sv = Sp[k4];
        const float* wp = Wb + (size_t)k4 * 128;
        float4 w0 = *(const float4*)(wp);
        float4 w1 = *(const float4*)(wp + 32);
        float4 w2 = *(const float4*)(wp + 64);
        float4 w3 = *(const float4*)(wp + 96);
        ax += sv.x * w0.x + sv.y * w1.x + sv.z * w2.x + sv.w * w3.x;
        ay += sv.x * w0.y + sv.y * w1.y + sv.z * w2.y + sv.w * w3.y;
        az += sv.x * w0.z + sv.y * w1.z + sv.z * w2.z + sv.w * w3.z;
        aw += sv.x * w0.w + sv.y * w1.w + sv.z * w2.w + sv.w * w3.w;
    }
    float4 accv; accv.x = ax; accv.y = ay; accv.z = az; accv.w = aw;
    red[nl][o4][ks] = accv;
    __syncthreads();
    if (ks != 0) return;
    // ---- epilogue (wave 0: 64 threads = 8 nodes x 8 o-quads) ----
    float4 a0 = red[nl][o4][0], a1 = red[nl][o4][1], a2 = red[nl][o4][2], a3 = red[nl][o4][3];
    float r0 = a0.x + a1.x + a2.x + a3.x;
    float r1 = a0.y + a1.y + a2.y + a3.y;
    float r2 = a0.z + a1.z + a2.z + a3.z;
    float r3 = a0.w + a1.w + a2.w + a3.w;
    int cnt = row_start[n + 1] - row_start[n];
    float d = (float)cnt; if (d < 1.f) d = 1.f;
    int ob = o4 * 4;
    float4 bcv = *(const float4*)(bc + ob);
    r0 = r0 / d + bcv.x; r1 = r1 / d + bcv.y; r2 = r2 / d + bcv.z; r3 = r3 / d + bcv.w;
    const float4* xr = (const float4*)(xin + (size_t)n * DIN);
#pragma unroll
    for (int i4 = 0; i4 < DIN / 4; i4++) {
        float4 xv = xr[i4];
        float4 wv0 = *(const float4*)(wr + (i4 * 4 + 0) * DOUT + ob);
        float4 wv1 = *(const float4*)(wr + (i4 * 4 + 1) * DOUT + ob);
        float4 wv2 = *(const float4*)(wr + (i4 * 4 + 2) * DOUT + ob);
        float4 wv3 = *(const float4*)(wr + (i4 * 4 + 3) * DOUT + ob);
        r0 += xv.x * wv0.x + xv.y * wv1.x + xv.z * wv2.x + xv.w * wv3.x;
        r1 += xv.x * wv0.y + xv.y * wv1.y + xv.z * wv2.y + xv.w * wv3.y;
        r2 += xv.x * wv0.z + xv.y * wv1.z + xv.z * wv2.z + xv.w * wv3.z;
        r3 += xv.x * wv0.w + xv.y * wv1.w + xv.z * wv2.w + xv.w * wv3.w;
    }
    r0 = r0 > 0.f ? r0 : expm1f(r0);
    r1 = r1 > 0.f ? r1 : expm1f(r1);
    r2 = r2 > 0.f ? r2 : expm1f(r2);
    r3 = r3 > 0.f ? r3 : expm1f(r3);
    if (FINAL) {
        int b = batch[n];
        atomicAdd(gsum + b * DOUT + ob + 0, r0);
        atomicAdd(gsum + b * DOUT + ob + 1, r1);
        atomicAdd(gsum + b * DOUT + ob + 2, r2);
        atomicAdd(gsum + b * DOUT + ob + 3, r3);
    } else {
        xout[n * DOUT + ob + 0] = r0;
        xout[n * DOUT + ob + 1] = r1;
        xout[n * DOUT + ob + 2] = r2;
        xout[n * DOUT + ob + 3] = r3;
    }
}

// ---- final fc; per-graph node counts via binary search on SORTED batch
__global__ void k_fc(const float* __restrict__ gsum, const int* __restrict__ batch,
                     const float* __restrict__ wfc, const float* __restrict__ bfc,
                     float* __restrict__ out) {
    int g = threadIdx.x;
    if (g >= GG) return;
    int lo = 0, hi = NN;
    while (lo < hi) { int mid = (lo + hi) >> 1; if (batch[mid] < g) lo = mid + 1; else hi = mid; }
    int lb = lo;
    lo = 0; hi = NN;
    while (lo < hi) { int mid = (lo + hi) >> 1; if (batch[mid] < g + 1) lo = mid + 1; else hi = mid; }
    float c = (float)(lo - lb); if (c < 1.f) c = 1.f;
    float acc = 0.f;
#pragma unroll
    for (int o = 0; o < DOUT; o++) acc += gsum[g * DOUT + o] * wfc[o];
    out[g] = acc / c + bfc[0];
}

extern "C" void kernel_launch(void* const* d_in, const int* in_sizes, int n_in,
                              void* d_out, int out_size, void* d_ws, size_t ws_size,
                              hipStream_t stream) {
    const float* x     = (const float*)d_in[0];
    const float* ea    = (const float*)d_in[1];
    const int*   ei    = (const int*)d_in[2];
    const int*   batch = (const int*)d_in[3];
    const float* w1_0 = (const float*)d_in[4];
    const float* b1_0 = (const float*)d_in[5];
    const float* g_0  = (const float*)d_in[6];
    const float* be_0 = (const float*)d_in[7];
    const float* w2_0 = (const float*)d_in[8];
    const float* b2_0 = (const float*)d_in[9];
    const float* wr_0 = (const float*)d_in[10];
    const float* bc_0 = (const float*)d_in[11];
    const float* w1_1 = (const float*)d_in[12];
    const float* b1_1 = (const float*)d_in[13];
    const float* g_1  = (const float*)d_in[14];
    const float* be_1 = (const float*)d_in[15];
    const float* w2_1 = (const float*)d_in[16];
    const float* b2_1 = (const float*)d_in[17];
    const float* wr_1 = (const float*)d_in[18];
    const float* bc_1 = (const float*)d_in[19];
    const float* wfc  = (const float*)d_in[20];
    const float* bfc  = (const float*)d_in[21];

    float* ws    = (float*)d_ws;
    int*   cur   = (int*)(ws + OFF_CUR);
    float* gsum  = ws + OFF_GSUM;
    int*   degc  = (int*)(ws + OFF_DEGC);
    float* mop   = ws + OFF_MOP;
    float* w1f0  = ws + OFF_W1F0;
    float* b1f0  = ws + OFF_B1F0;
    float* w1f1  = ws + OFF_W1F1;
    float* b1f1  = ws + OFF_B1F1;
    int*   row   = (int*)(ws + OFF_ROW);
    int*   csrc  = (int*)(ws + OFF_SRC);
    int*   ceid  = (int*)(ws + OFF_EID);
    float* wt0   = ws + OFF_WT0;
    float* wt1   = ws + OFF_WT1;
    float* hcsr  = ws + OFF_H;
    float* Sbuf  = ws + OFF_S;
    float* x1    = ws + OFF_X1;

    hipMemsetAsync(ws, 0, (size_t)ZERO_FLOATS * sizeof(float), stream);

    k_momdeg<<<64, 256, 0, stream>>>(ea, ei, mop, degc);
    k_scan<<<1, 256, 0, stream>>>(degc, row);
    k_scatter<<<(EE + 255) / 256, 256, 0, stream>>>(ei, row, cur, csrc, ceid);
    k_prep<<<193, 256, 0, stream>>>(mop, w1_0, b1_0, g_0, be_0, w1_1, b1_1, g_1, be_1,
                                    w2_0, b2_0, w2_1, b2_1,
                                    w1f0, b1f0, w1f1, b1f1, wt0, wt1);

    // ---- layer 0 (din=16, K=512)
    k_h<<<EE / 8, 256, 0, stream>>>(ea, ceid, w1f0, b1f0, hcsr);
    k_sedge<16, 8, 512><<<NN / 4, 256, 0, stream>>>(row, csrc, hcsr, x, Sbuf);
    k_gemm<16, 512, false><<<NN / 8, 256, 0, stream>>>(Sbuf, wt0, row, x, wr_0, bc_0,
                                                       batch, x1, gsum);

    // ---- layer 1 (din=32, K=1024), pool fused into epilogue
    k_h<<<EE / 8, 256, 0, stream>>>(ea, ceid, w1f1, b1f1, hcsr);
    k_sedge<32, 16, 1024><<<NN / 4, 256, 0, stream>>>(row, csrc, hcsr, x1, Sbuf);
    k_gemm<32, 1024, true><<<NN / 8, 256, 0, stream>>>(Sbuf, wt1, row, x1, wr_1, bc_1,
                                                       batch, nullptr, gsum);

    // ---- fc (counts via binary search on sorted batch)
    k_fc<<<1, 128, 0, stream>>>(gsum, batch, wfc, bfc, (float*)d_out);
}

// Round 11
// 305.811 us; speedup vs baseline: 1.4839x; 1.0729x over previous
//
#include <hip/hip_runtime.h>
#include <math.h>

// Problem constants (fixed by reference)
#define NN   10000
#define EE   160000
#define GG   128
#define HIDK 25
#define DOUT 32
#define EPSBN 1e-5f

// ---------------- workspace layout (float offsets) ----------------
// zeroed region (one hipMemsetAsync):
#define OFF_CUR   0          // NN ints (scatter cursors), pad 10016
#define OFF_GSUM  10016      // G*32 = 4096
#define OFF_DEGC  14112      // NN ints, pad 10016
#define ZERO_FLOATS 24128
// non-zeroed:
#define OFF_MOP   24128      // 64*12
#define OFF_W1F0  24896      // 80
#define OFF_B1F0  24976      // 32
#define OFF_W1F1  25008      // 80
#define OFF_B1F1  25088      // 32
#define OFF_ROW   25120      // NN+1 ints, pad 10016
#define OFF_SRC   35136      // E ints
#define OFF_EID   195136     // E ints
#define OFF_WT0   355136     // 512*32  = 16384  (W[K][o], layer0)
#define OFF_WT1   371520     // 1024*32 = 32768  (W[K][o], layer1)
#define OFF_H     404288     // E*32 = 5,120,000 (h in CSR-slot order, per layer)
#define OFF_S     5524288    // N*1024 = 10,240,000 (S, shared by both layers)
#define OFF_X1    15764288   // N*32
#define TOTAL_FLOATS 16084288 // ~64.3 MB of d_ws

__device__ inline float wave_red(float v) {
    for (int off = 32; off; off >>= 1) v += __shfl_down(v, off);
    return v;
}

// ---- moments partials (64 blocks, atomic-free) + in-degree atomics, one pass
__global__ void k_momdeg(const float* __restrict__ ea, const int* __restrict__ ei,
                         float* __restrict__ mop, int* __restrict__ degc) {
    __shared__ float ls[4][9];
    float s[9];
#pragma unroll
    for (int j = 0; j < 9; j++) s[j] = 0.f;
    int t = threadIdx.x;
    for (int e = blockIdx.x * 256 + t; e < EE; e += 64 * 256) {
        float a0 = ea[3 * e], a1 = ea[3 * e + 1], a2 = ea[3 * e + 2];
        s[0] += a0; s[1] += a1; s[2] += a2;
        s[3] += a0 * a0; s[4] += a0 * a1; s[5] += a0 * a2;
        s[6] += a1 * a1; s[7] += a1 * a2; s[8] += a2 * a2;
        atomicAdd(degc + ei[EE + e], 1);
    }
    int w = t >> 6, lane = t & 63;
#pragma unroll
    for (int j = 0; j < 9; j++) {
        float r = wave_red(s[j]);
        if (lane == 0) ls[w][j] = r;
    }
    __syncthreads();
    if (t < 9) mop[blockIdx.x * 12 + t] = ls[0][t] + ls[1][t] + ls[2][t] + ls[3][t];
}

// ---- single-block exclusive scan of degc -> row_start[NN+1]
__global__ void k_scan(const int* __restrict__ degc, int* __restrict__ row_start) {
    __shared__ int p[256];
    int t = threadIdx.x;
    const int CHUNK = 40;                 // 250*40 == 10000 exactly
    int base = t * CHUNK;
    int sum = 0;
    if (t < 250) {
        for (int i = 0; i < CHUNK; i++) sum += degc[base + i];
    }
    p[t] = sum;
    __syncthreads();
    for (int off = 1; off < 256; off <<= 1) {
        int v = (t >= off) ? p[t - off] : 0;
        __syncthreads();
        p[t] += v;
        __syncthreads();
    }
    int excl = p[t] - sum;
    if (t < 250) {
        int run = excl;
        for (int i = 0; i < CHUNK; i++) {
            row_start[base + i] = run;
            run += degc[base + i];
        }
    }
    if (t == 0) row_start[NN] = EE;
}

// ---- scatter edges into CSR slots
__global__ void k_scatter(const int* __restrict__ ei, const int* __restrict__ row_start,
                          int* __restrict__ cur, int* __restrict__ csr_src,
                          int* __restrict__ csr_eid) {
    int e = blockIdx.x * blockDim.x + threadIdx.x;
    if (e >= EE) return;
    int d = ei[EE + e];
    int pos = atomicAdd(cur + d, 1);
    int idx = row_start[d] + pos;
    csr_src[idx] = ei[e];
    csr_eid[idx] = e;
}

// ---- merged prep: blocks 0..191 pack W[K][o] for both layers; block 192 folds BN.
// K is the S-layout index from k_sedge: K = lane*KPL + j, lane = (kh,il):
//   il = lane & (DIN-1), kh = lane / DIN, k = kh*KPL + j.
// k<25 -> w2[k][il][o] ; k==25 -> b2[il][o] ; k>25 -> 0.
__global__ void k_prep(const float* __restrict__ mop,
                       const float* __restrict__ w1_0, const float* __restrict__ b1_0,
                       const float* __restrict__ g_0, const float* __restrict__ be_0,
                       const float* __restrict__ w1_1, const float* __restrict__ b1_1,
                       const float* __restrict__ g_1, const float* __restrict__ be_1,
                       const float* __restrict__ w2_0, const float* __restrict__ b2_0,
                       const float* __restrict__ w2_1, const float* __restrict__ b2_1,
                       float* __restrict__ w1f0, float* __restrict__ b1f0,
                       float* __restrict__ w1f1, float* __restrict__ b1f1,
                       float* __restrict__ wt0, float* __restrict__ wt1) {
    int b = blockIdx.x, t = threadIdx.x;
    if (b < 192) {
        int idx = b * 256 + t;
        if (idx < 512 * 32) {                       // layer0: KT=512, DIN=16, KPL=8
            int K = idx >> 5, o = idx & 31;
            int lane = K >> 3, j = K & 7;
            int kh = lane >> 4, il = lane & 15;
            int k = kh * 8 + j;
            float v = 0.f;
            if (k < HIDK) v = w2_0[(k * 16 + il) * DOUT + o];
            else if (k == HIDK) v = b2_0[il * DOUT + o];
            wt0[idx] = v;
        } else {                                    // layer1: KT=1024, DIN=32, KPL=16
            int idx2 = idx - 512 * 32;
            int K = idx2 >> 5, o = idx2 & 31;
            int lane = K >> 4, j = K & 15;
            int kh = lane >> 5, il = lane & 31;
            int k = kh * 16 + j;
            float v = 0.f;
            if (k < HIDK) v = w2_1[(k * 32 + il) * DOUT + o];
            else if (k == HIDK) v = b2_1[il * DOUT + o];
            wt1[idx2] = v;
        }
        return;
    }
    // ---- block 192: fold BN for both layers
    __shared__ float mo[9];
    if (t < 9) {
        float s = 0.f;
        for (int bb = 0; bb < 64; bb++) s += mop[bb * 12 + t];
        mo[t] = s;
    }
    __syncthreads();
    int grp = t >> 5, j = t & 31;
    if (t >= 64 || j >= HIDK) return;
    const float* w1 = grp ? w1_1 : w1_0;
    const float* b1 = grp ? b1_1 : b1_0;
    const float* g  = grp ? g_1  : g_0;
    const float* be = grp ? be_1 : be_0;
    float* w1f = grp ? w1f1 : w1f0;
    float* b1f = grp ? b1f1 : b1f0;
    const float inv = 1.0f / (float)EE;
    float m0 = mo[0] * inv, m1 = mo[1] * inv, m2 = mo[2] * inv;
    float c00 = mo[3] * inv - m0 * m0, c01 = mo[4] * inv - m0 * m1, c02 = mo[5] * inv - m0 * m2;
    float c11 = mo[6] * inv - m1 * m1, c12 = mo[7] * inv - m1 * m2, c22 = mo[8] * inv - m2 * m2;
    float w0 = w1[j], wa = w1[25 + j], wb = w1[50 + j];
    float mean = m0 * w0 + m1 * wa + m2 * wb + b1[j];
    float var = w0 * w0 * c00 + wa * wa * c11 + wb * wb * c22
              + 2.f * (w0 * wa * c01 + w0 * wb * c02 + wa * wb * c12);
    float sc = g[j] * rsqrtf(var + EPSBN);
    w1f[j] = w0 * sc; w1f[25 + j] = wa * sc; w1f[50 + j] = wb * sc;
    b1f[j] = (b1[j] - mean) * sc + be[j];
}

// ---- h in CSR-slot order: hcsr[slot][k] = relu(ea[eid]@w1f+b1f)[k]; k=25 -> 1; pad -> 0
__global__ void k_h(const float* __restrict__ ea, const int* __restrict__ csr_eid,
                    const float* __restrict__ w1f, const float* __restrict__ b1f,
                    float* __restrict__ hcsr) {
    int t = threadIdx.x;
    int slot = blockIdx.x * 8 + (t >> 5);   // 20000 blocks exactly
    int k = t & 31;
    int e = csr_eid[slot];
    float v = 0.f;
    if (k < HIDK) {
        float a0 = ea[3 * e], a1 = ea[3 * e + 1], a2 = ea[3 * e + 2];
        v = a0 * w1f[k] + a1 * w1f[25 + k] + a2 * w1f[50 + k] + b1f[k];
        v = v > 0.f ? v : 0.f;
    } else if (k == HIDK) {
        v = 1.0f;
    }
    hcsr[(size_t)slot * 32 + k] = v;
}

// ---- Phase A: S[n][K] = sum_{edges of n} h[slot][k] * x[src, i]
// One wave per node, 4-edge unroll, S in registers, no LDS/barriers.
// Lane layout: il = lane & (DIN-1), kh = lane/DIN owns k = kh*KPL + j.
// S stored lane-major: S[n*KT + lane*KPL + j] -> KPL/4 coalesced b128 stores.
template <int DIN, int KPL, int KT>
__global__ void k_sedge(const int* __restrict__ row_start, const int* __restrict__ csr_src,
                        const float* __restrict__ hcsr, const float* __restrict__ xin,
                        float* __restrict__ S) {
    int t = threadIdx.x;
    int w = t >> 6, lane = t & 63;
    int n = blockIdx.x * 4 + w;            // grid 2500
    int start = row_start[n], end = row_start[n + 1];
    int il = lane & (DIN - 1);
    int kh = lane / DIN;
    float s[KPL];
#pragma unroll
    for (int j = 0; j < KPL; j++) s[j] = 0.f;

    for (int p = start; p < end; p += 4) {
        int e1 = end - 1;
        int q0 = p;
        int q1 = (p + 1 < end) ? p + 1 : e1;
        int q2 = (p + 2 < end) ? p + 2 : e1;
        int q3 = (p + 3 < end) ? p + 3 : e1;
        bool v1 = p + 1 < end, v2 = p + 2 < end, v3 = p + 3 < end;
        int s0 = csr_src[q0], s1 = csr_src[q1], s2 = csr_src[q2], s3 = csr_src[q3];
        const float4* h0 = (const float4*)(hcsr + (size_t)q0 * 32 + kh * KPL);
        const float4* h1 = (const float4*)(hcsr + (size_t)q1 * 32 + kh * KPL);
        const float4* h2 = (const float4*)(hcsr + (size_t)q2 * 32 + kh * KPL);
        const float4* h3 = (const float4*)(hcsr + (size_t)q3 * 32 + kh * KPL);
        float4 H0[KPL / 4], H1[KPL / 4], H2[KPL / 4], H3[KPL / 4];
#pragma unroll
        for (int j4 = 0; j4 < KPL / 4; j4++) {
            H0[j4] = h0[j4]; H1[j4] = h1[j4]; H2[j4] = h2[j4]; H3[j4] = h3[j4];
        }
        float x0 = xin[s0 * DIN + il];
        float x1 = v1 ? xin[s1 * DIN + il] : 0.f;
        float x2 = v2 ? xin[s2 * DIN + il] : 0.f;
        float x3 = v3 ? xin[s3 * DIN + il] : 0.f;
#pragma unroll
        for (int j4 = 0; j4 < KPL / 4; j4++) {
            s[j4 * 4 + 0] += H0[j4].x * x0; s[j4 * 4 + 1] += H0[j4].y * x0;
            s[j4 * 4 + 2] += H0[j4].z * x0; s[j4 * 4 + 3] += H0[j4].w * x0;
        }
#pragma unroll
        for (int j4 = 0; j4 < KPL / 4; j4++) {
            s[j4 * 4 + 0] += H1[j4].x * x1; s[j4 * 4 + 1] += H1[j4].y * x1;
            s[j4 * 4 + 2] += H1[j4].z * x1; s[j4 * 4 + 3] += H1[j4].w * x1;
        }
#pragma unroll
        for (int j4 = 0; j4 < KPL / 4; j4++) {
            s[j4 * 4 + 0] += H2[j4].x * x2; s[j4 * 4 + 1] += H2[j4].y * x2;
            s[j4 * 4 + 2] += H2[j4].z * x2; s[j4 * 4 + 3] += H2[j4].w * x2;
        }
#pragma unroll
        for (int j4 = 0; j4 < KPL / 4; j4++) {
            s[j4 * 4 + 0] += H3[j4].x * x3; s[j4 * 4 + 1] += H3[j4].y * x3;
            s[j4 * 4 + 2] += H3[j4].z * x3; s[j4 * 4 + 3] += H3[j4].w * x3;
        }
    }
    float4* Sp = (float4*)(S + (size_t)n * KT + lane * KPL);
#pragma unroll
    for (int j4 = 0; j4 < KPL / 4; j4++) {
        float4 v; v.x = s[j4 * 4]; v.y = s[j4 * 4 + 1]; v.z = s[j4 * 4 + 2]; v.w = s[j4 * 4 + 3];
        Sp[j4] = v;
    }
}

// ---- Phase B: LDS-tiled GEMM out[16n x 32o] = S . W + epilogue.
// R11: 16 nodes/block (grid 625 exact). Each wave owns a K-quarter, staged
// into wave-private LDS in 64-k chunks (coalesced b128 global -> b128 ds_write,
// no transpose). Lane tile 2n x 4o: per k4 = 2 ds_read_b128 (S broadcast,
// conflict-free) + 4 coalesced W float4 (L1-hot) + 32 FMA -> VALU-bound.
// Cross-wave K-reduce via LDS; epilogue fuses deg-divide/root/ELU/pool.
template <int DIN, int KT, bool FINAL>
__global__ void k_gemm(const float* __restrict__ S, const float* __restrict__ WT,
                       const int* __restrict__ row_start, const float* __restrict__ xin,
                       const float* __restrict__ wr, const float* __restrict__ bc,
                       const int* __restrict__ batch, float* __restrict__ xout,
                       float* __restrict__ gsum) {
    __shared__ __align__(16) float Sl[4][16][68];   // wave-private S chunk [16n][64k]
    __shared__ __align__(16) float redf[4][16][36]; // cross-wave partials
    int t = threadIdx.x;
    int w = t >> 6, lane = t & 63;
    int nb = blockIdx.x * 16;              // grid 625 exact
    int ng = lane >> 3, og = lane & 7;     // 8 n-groups x 8 o-groups
    int n0 = ng * 2, n1 = n0 + 1;
    const int KW = KT / 4;                 // per-wave K range (256 / 128)
    int kbase = w * KW;
    float a0 = 0.f, a1 = 0.f, a2 = 0.f, a3 = 0.f;
    float b0 = 0.f, b1 = 0.f, b2 = 0.f, b3 = 0.f;
    int sn = lane >> 2, kq = lane & 3;     // staging map: 16 n x 4 k-quarters
    for (int c = 0; c < KW / 64; c++) {
        int kc = kbase + c * 64;
        const float4* gs = (const float4*)(S + (size_t)(nb + sn) * KT + kc + kq * 16);
        float4* lsd = (float4*)&Sl[w][sn][kq * 16];
        lsd[0] = gs[0]; lsd[1] = gs[1]; lsd[2] = gs[2]; lsd[3] = gs[3];
        __syncthreads();
        const float* wp0 = WT + (size_t)kc * 32 + og * 4;
#pragma unroll 4
        for (int kk = 0; kk < 64; kk += 4) {
            float4 s0 = *(const float4*)&Sl[w][n0][kk];
            float4 s1 = *(const float4*)&Sl[w][n1][kk];
            const float* wp = wp0 + kk * 32;
            float4 w0 = *(const float4*)(wp);
            float4 w1 = *(const float4*)(wp + 32);
            float4 w2 = *(const float4*)(wp + 64);
            float4 w3 = *(const float4*)(wp + 96);
            a0 += s0.x * w0.x + s0.y * w1.x + s0.z * w2.x + s0.w * w3.x;
            a1 += s0.x * w0.y + s0.y * w1.y + s0.z * w2.y + s0.w * w3.y;
            a2 += s0.x * w0.z + s0.y * w1.z + s0.z * w2.z + s0.w * w3.z;
            a3 += s0.x * w0.w + s0.y * w1.w + s0.z * w2.w + s0.w * w3.w;
            b0 += s1.x * w0.x + s1.y * w1.x + s1.z * w2.x + s1.w * w3.x;
            b1 += s1.x * w0.y + s1.y * w1.y + s1.z * w2.y + s1.w * w3.y;
            b2 += s1.x * w0.z + s1.y * w1.z + s1.z * w2.z + s1.w * w3.z;
            b3 += s1.x * w0.w + s1.y * w1.w + s1.z * w2.w + s1.w * w3.w;
        }
        __syncthreads();
    }
    float4 va; va.x = a0; va.y = a1; va.z = a2; va.w = a3;
    float4 vb; vb.x = b0; vb.y = b1; vb.z = b2; vb.w = b3;
    *(float4*)&redf[w][n0][og * 4] = va;
    *(float4*)&redf[w][n1][og * 4] = vb;
    __syncthreads();
    if (t >= 128) return;
    // ---- epilogue: 128 threads = 16 nodes x 8 o-quads ----
    int nl = t >> 3, og2 = t & 7, ob = og2 * 4;
    int n = nb + nl;
    float4 p0 = *(const float4*)&redf[0][nl][ob];
    float4 p1 = *(const float4*)&redf[1][nl][ob];
    float4 p2 = *(const float4*)&redf[2][nl][ob];
    float4 p3 = *(const float4*)&redf[3][nl][ob];
    float r0 = p0.x + p1.x + p2.x + p3.x;
    float r1 = p0.y + p1.y + p2.y + p3.y;
    float r2 = p0.z + p1.z + p2.z + p3.z;
    float r3 = p0.w + p1.w + p2.w + p3.w;
    int cnt = row_start[n + 1] - row_start[n];
    float d = (float)cnt; if (d < 1.f) d = 1.f;
    float4 bcv = *(const float4*)(bc + ob);
    r0 = r0 / d + bcv.x; r1 = r1 / d + bcv.y; r2 = r2 / d + bcv.z; r3 = r3 / d + bcv.w;
    const float4* xr = (const float4*)(xin + (size_t)n * DIN);
#pragma unroll
    for (int i4 = 0; i4 < DIN / 4; i4++) {
        float4 xv = xr[i4];
        float4 wv0 = *(const float4*)(wr + (i4 * 4 + 0) * DOUT + ob);
        float4 wv1 = *(const float4*)(wr + (i4 * 4 + 1) * DOUT + ob);
        float4 wv2 = *(const float4*)(wr + (i4 * 4 + 2) * DOUT + ob);
        float4 wv3 = *(const float4*)(wr + (i4 * 4 + 3) * DOUT + ob);
        r0 += xv.x * wv0.x + xv.y * wv1.x + xv.z * wv2.x + xv.w * wv3.x;
        r1 += xv.x * wv0.y + xv.y * wv1.y + xv.z * wv2.y + xv.w * wv3.y;
        r2 += xv.x * wv0.z + xv.y * wv1.z + xv.z * wv2.z + xv.w * wv3.z;
        r3 += xv.x * wv0.w + xv.y * wv1.w + xv.z * wv2.w + xv.w * wv3.w;
    }
    r0 = r0 > 0.f ? r0 : expm1f(r0);
    r1 = r1 > 0.f ? r1 : expm1f(r1);
    r2 = r2 > 0.f ? r2 : expm1f(r2);
    r3 = r3 > 0.f ? r3 : expm1f(r3);
    if (FINAL) {
        int b = batch[n];
        atomicAdd(gsum + b * DOUT + ob + 0, r0);
        atomicAdd(gsum + b * DOUT + ob + 1, r1);
        atomicAdd(gsum + b * DOUT + ob + 2, r2);
        atomicAdd(gsum + b * DOUT + ob + 3, r3);
    } else {
        xout[n * DOUT + ob + 0] = r0;
        xout[n * DOUT + ob + 1] = r1;
        xout[n * DOUT + ob + 2] = r2;
        xout[n * DOUT + ob + 3] = r3;
    }
}

// ---- final fc; per-graph node counts via binary search on SORTED batch
__global__ void k_fc(const float* __restrict__ gsum, const int* __restrict__ batch,
                     const float* __restrict__ wfc, const float* __restrict__ bfc,
                     float* __restrict__ out) {
    int g = threadIdx.x;
    if (g >= GG) return;
    int lo = 0, hi = NN;
    while (lo < hi) { int mid = (lo + hi) >> 1; if (batch[mid] < g) lo = mid + 1; else hi = mid; }
    int lb = lo;
    lo = 0; hi = NN;
    while (lo < hi) { int mid = (lo + hi) >> 1; if (batch[mid] < g + 1) lo = mid + 1; else hi = mid; }
    float c = (float)(lo - lb); if (c < 1.f) c = 1.f;
    float acc = 0.f;
#pragma unroll
    for (int o = 0; o < DOUT; o++) acc += gsum[g * DOUT + o] * wfc[o];
    out[g] = acc / c + bfc[0];
}

extern "C" void kernel_launch(void* const* d_in, const int* in_sizes, int n_in,
                              void* d_out, int out_size, void* d_ws, size_t ws_size,
                              hipStream_t stream) {
    const float* x     = (const float*)d_in[0];
    const float* ea    = (const float*)d_in[1];
    const int*   ei    = (const int*)d_in[2];
    const int*   batch = (const int*)d_in[3];
    const float* w1_0 = (const float*)d_in[4];
    const float* b1_0 = (const float*)d_in[5];
    const float* g_0  = (const float*)d_in[6];
    const float* be_0 = (const float*)d_in[7];
    const float* w2_0 = (const float*)d_in[8];
    const float* b2_0 = (const float*)d_in[9];
    const float* wr_0 = (const float*)d_in[10];
    const float* bc_0 = (const float*)d_in[11];
    const float* w1_1 = (const float*)d_in[12];
    const float* b1_1 = (const float*)d_in[13];
    const float* g_1  = (const float*)d_in[14];
    const float* be_1 = (const float*)d_in[15];
    const float* w2_1 = (const float*)d_in[16];
    const float* b2_1 = (const float*)d_in[17];
    const float* wr_1 = (const float*)d_in[18];
    const float* bc_1 = (const float*)d_in[19];
    const float* wfc  = (const float*)d_in[20];
    const float* bfc  = (const float*)d_in[21];

    float* ws    = (float*)d_ws;
    int*   cur   = (int*)(ws + OFF_CUR);
    float* gsum  = ws + OFF_GSUM;
    int*   degc  = (int*)(ws + OFF_DEGC);
    float* mop   = ws + OFF_MOP;
    float* w1f0  = ws + OFF_W1F0;
    float* b1f0  = ws + OFF_B1F0;
    float* w1f1  = ws + OFF_W1F1;
    float* b1f1  = ws + OFF_B1F1;
    int*   row   = (int*)(ws + OFF_ROW);
    int*   csrc  = (int*)(ws + OFF_SRC);
    int*   ceid  = (int*)(ws + OFF_EID);
    float* wt0   = ws + OFF_WT0;
    float* wt1   = ws + OFF_WT1;
    float* hcsr  = ws + OFF_H;
    float* Sbuf  = ws + OFF_S;
    float* x1    = ws + OFF_X1;

    hipMemsetAsync(ws, 0, (size_t)ZERO_FLOATS * sizeof(float), stream);

    k_momdeg<<<64, 256, 0, stream>>>(ea, ei, mop, degc);
    k_scan<<<1, 256, 0, stream>>>(degc, row);
    k_scatter<<<(EE + 255) / 256, 256, 0, stream>>>(ei, row, cur, csrc, ceid);
    k_prep<<<193, 256, 0, stream>>>(mop, w1_0, b1_0, g_0, be_0, w1_1, b1_1, g_1, be_1,
                                    w2_0, b2_0, w2_1, b2_1,
                                    w1f0, b1f0, w1f1, b1f1, wt0, wt1);

    // ---- layer 0 (din=16, K=512)
    k_h<<<EE / 8, 256, 0, stream>>>(ea, ceid, w1f0, b1f0, hcsr);
    k_sedge<16, 8, 512><<<NN / 4, 256, 0, stream>>>(row, csrc, hcsr, x, Sbuf);
    k_gemm<16, 512, false><<<NN / 16, 256, 0, stream>>>(Sbuf, wt0, row, x, wr_0, bc_0,
                                                        batch, x1, gsum);

    // ---- layer 1 (din=32, K=1024), pool fused into epilogue
    k_h<<<EE / 8, 256, 0, stream>>>(ea, ceid, w1f1, b1f1, hcsr);
    k_sedge<32, 16, 1024><<<NN / 4, 256, 0, stream>>>(row, csrc, hcsr, x1, Sbuf);
    k_gemm<32, 1024, true><<<NN / 16, 256, 0, stream>>>(Sbuf, wt1, row, x1, wr_1, bc_1,
                                                        batch, nullptr, gsum);

    // ---- fc (counts via binary search on sorted batch)
    k_fc<<<1, 128, 0, stream>>>(gsum, batch, wfc, bfc, (float*)d_out);
}

// Round 12
// 302.103 us; speedup vs baseline: 1.5021x; 1.0123x over previous
//
#include <hip/hip_runtime.h>
#include <math.h>

// Problem constants (fixed by reference)
#define NN   10000
#define EE   160000
#define GG   128
#define HIDK 25
#define DOUT 32
#define EPSBN 1e-5f

// ---------------- workspace layout (float offsets) ----------------
// zeroed region (one hipMemsetAsync):
#define OFF_CUR   0          // NN ints (scatter cursors), pad 10016
#define OFF_GSUM  10016      // G*32 = 4096
#define OFF_DEGC  14112      // NN ints, pad 10016
#define ZERO_FLOATS 24128
// non-zeroed:
#define OFF_MOP   24128      // 64*12
#define OFF_W1F0  24896      // 80
#define OFF_B1F0  24976      // 32
#define OFF_W1F1  25008      // 80
#define OFF_B1F1  25088      // 32
#define OFF_ROW   25120      // NN+1 ints, pad 10016
#define OFF_SRC   35136      // E ints
#define OFF_EID   195136     // E ints
#define OFF_WT0   355136     // 512*32  = 16384  (W[K][o], layer0)
#define OFF_WT1   371520     // 1024*32 = 32768  (W[K][o], layer1)
#define OFF_H     404288     // E*32 = 5,120,000 (h in CSR-slot order, per layer)
#define OFF_S     5524288    // N*1024 = 10,240,000 (S, shared by both layers)
#define OFF_X1    15764288   // N*32
#define TOTAL_FLOATS 16084288 // ~64.3 MB of d_ws

__device__ inline float wave_red(float v) {
    for (int off = 32; off; off >>= 1) v += __shfl_down(v, off);
    return v;
}

// ---- moments partials (64 blocks, atomic-free) + in-degree atomics, one pass
__global__ void k_momdeg(const float* __restrict__ ea, const int* __restrict__ ei,
                         float* __restrict__ mop, int* __restrict__ degc) {
    __shared__ float ls[4][9];
    float s[9];
#pragma unroll
    for (int j = 0; j < 9; j++) s[j] = 0.f;
    int t = threadIdx.x;
    for (int e = blockIdx.x * 256 + t; e < EE; e += 64 * 256) {
        float a0 = ea[3 * e], a1 = ea[3 * e + 1], a2 = ea[3 * e + 2];
        s[0] += a0; s[1] += a1; s[2] += a2;
        s[3] += a0 * a0; s[4] += a0 * a1; s[5] += a0 * a2;
        s[6] += a1 * a1; s[7] += a1 * a2; s[8] += a2 * a2;
        atomicAdd(degc + ei[EE + e], 1);
    }
    int w = t >> 6, lane = t & 63;
#pragma unroll
    for (int j = 0; j < 9; j++) {
        float r = wave_red(s[j]);
        if (lane == 0) ls[w][j] = r;
    }
    __syncthreads();
    if (t < 9) mop[blockIdx.x * 12 + t] = ls[0][t] + ls[1][t] + ls[2][t] + ls[3][t];
}

// ---- single-block exclusive scan of degc -> row_start[NN+1]
__global__ void k_scan(const int* __restrict__ degc, int* __restrict__ row_start) {
    __shared__ int p[256];
    int t = threadIdx.x;
    const int CHUNK = 40;                 // 250*40 == 10000 exactly
    int base = t * CHUNK;
    int sum = 0;
    if (t < 250) {
        for (int i = 0; i < CHUNK; i++) sum += degc[base + i];
    }
    p[t] = sum;
    __syncthreads();
    for (int off = 1; off < 256; off <<= 1) {
        int v = (t >= off) ? p[t - off] : 0;
        __syncthreads();
        p[t] += v;
        __syncthreads();
    }
    int excl = p[t] - sum;
    if (t < 250) {
        int run = excl;
        for (int i = 0; i < CHUNK; i++) {
            row_start[base + i] = run;
            run += degc[base + i];
        }
    }
    if (t == 0) row_start[NN] = EE;
}

// ---- scatter edges into CSR slots
__global__ void k_scatter(const int* __restrict__ ei, const int* __restrict__ row_start,
                          int* __restrict__ cur, int* __restrict__ csr_src,
                          int* __restrict__ csr_eid) {
    int e = blockIdx.x * blockDim.x + threadIdx.x;
    if (e >= EE) return;
    int d = ei[EE + e];
    int pos = atomicAdd(cur + d, 1);
    int idx = row_start[d] + pos;
    csr_src[idx] = ei[e];
    csr_eid[idx] = e;
}

// ---- merged prep: blocks 0..191 pack W[K][o] for both layers; block 192 folds BN.
// K is the S-layout index from k_sedge: K = lane*KPL + j, lane = (kh,il):
//   il = lane & (DIN-1), kh = lane / DIN, k = kh*KPL + j.
// k<25 -> w2[k][il][o] ; k==25 -> b2[il][o] ; k>25 -> 0.
__global__ void k_prep(const float* __restrict__ mop,
                       const float* __restrict__ w1_0, const float* __restrict__ b1_0,
                       const float* __restrict__ g_0, const float* __restrict__ be_0,
                       const float* __restrict__ w1_1, const float* __restrict__ b1_1,
                       const float* __restrict__ g_1, const float* __restrict__ be_1,
                       const float* __restrict__ w2_0, const float* __restrict__ b2_0,
                       const float* __restrict__ w2_1, const float* __restrict__ b2_1,
                       float* __restrict__ w1f0, float* __restrict__ b1f0,
                       float* __restrict__ w1f1, float* __restrict__ b1f1,
                       float* __restrict__ wt0, float* __restrict__ wt1) {
    int b = blockIdx.x, t = threadIdx.x;
    if (b < 192) {
        int idx = b * 256 + t;
        if (idx < 512 * 32) {                       // layer0: KT=512, DIN=16, KPL=8
            int K = idx >> 5, o = idx & 31;
            int lane = K >> 3, j = K & 7;
            int kh = lane >> 4, il = lane & 15;
            int k = kh * 8 + j;
            float v = 0.f;
            if (k < HIDK) v = w2_0[(k * 16 + il) * DOUT + o];
            else if (k == HIDK) v = b2_0[il * DOUT + o];
            wt0[idx] = v;
        } else {                                    // layer1: KT=1024, DIN=32, KPL=16
            int idx2 = idx - 512 * 32;
            int K = idx2 >> 5, o = idx2 & 31;
            int lane = K >> 4, j = K & 15;
            int kh = lane >> 5, il = lane & 31;
            int k = kh * 16 + j;
            float v = 0.f;
            if (k < HIDK) v = w2_1[(k * 32 + il) * DOUT + o];
            else if (k == HIDK) v = b2_1[il * DOUT + o];
            wt1[idx2] = v;
        }
        return;
    }
    // ---- block 192: fold BN for both layers
    __shared__ float mo[9];
    if (t < 9) {
        float s = 0.f;
        for (int bb = 0; bb < 64; bb++) s += mop[bb * 12 + t];
        mo[t] = s;
    }
    __syncthreads();
    int grp = t >> 5, j = t & 31;
    if (t >= 64 || j >= HIDK) return;
    const float* w1 = grp ? w1_1 : w1_0;
    const float* b1 = grp ? b1_1 : b1_0;
    const float* g  = grp ? g_1  : g_0;
    const float* be = grp ? be_1 : be_0;
    float* w1f = grp ? w1f1 : w1f0;
    float* b1f = grp ? b1f1 : b1f0;
    const float inv = 1.0f / (float)EE;
    float m0 = mo[0] * inv, m1 = mo[1] * inv, m2 = mo[2] * inv;
    float c00 = mo[3] * inv - m0 * m0, c01 = mo[4] * inv - m0 * m1, c02 = mo[5] * inv - m0 * m2;
    float c11 = mo[6] * inv - m1 * m1, c12 = mo[7] * inv - m1 * m2, c22 = mo[8] * inv - m2 * m2;
    float w0 = w1[j], wa = w1[25 + j], wb = w1[50 + j];
    float mean = m0 * w0 + m1 * wa + m2 * wb + b1[j];
    float var = w0 * w0 * c00 + wa * wa * c11 + wb * wb * c22
              + 2.f * (w0 * wa * c01 + w0 * wb * c02 + wa * wb * c12);
    float sc = g[j] * rsqrtf(var + EPSBN);
    w1f[j] = w0 * sc; w1f[25 + j] = wa * sc; w1f[50 + j] = wb * sc;
    b1f[j] = (b1[j] - mean) * sc + be[j];
}

// ---- h in CSR-slot order: hcsr[slot][k] = relu(ea[eid]@w1f+b1f)[k]; k=25 -> 1; pad -> 0
__global__ void k_h(const float* __restrict__ ea, const int* __restrict__ csr_eid,
                    const float* __restrict__ w1f, const float* __restrict__ b1f,
                    float* __restrict__ hcsr) {
    int t = threadIdx.x;
    int slot = blockIdx.x * 8 + (t >> 5);   // 20000 blocks exactly
    int k = t & 31;
    int e = csr_eid[slot];
    float v = 0.f;
    if (k < HIDK) {
        float a0 = ea[3 * e], a1 = ea[3 * e + 1], a2 = ea[3 * e + 2];
        v = a0 * w1f[k] + a1 * w1f[25 + k] + a2 * w1f[50 + k] + b1f[k];
        v = v > 0.f ? v : 0.f;
    } else if (k == HIDK) {
        v = 1.0f;
    }
    hcsr[(size_t)slot * 32 + k] = v;
}

// ---- Phase A: S[n][K] = sum_{edges of n} h[slot][k] * x[src, i]
// One wave per node, 4-edge unroll, S in registers, no LDS/barriers.
// Lane layout: il = lane & (DIN-1), kh = lane/DIN owns k = kh*KPL + j.
// S stored lane-major: S[n*KT + lane*KPL + j] -> KPL/4 coalesced b128 stores.
template <int DIN, int KPL, int KT>
__global__ void k_sedge(const int* __restrict__ row_start, const int* __restrict__ csr_src,
                        const float* __restrict__ hcsr, const float* __restrict__ xin,
                        float* __restrict__ S) {
    int t = threadIdx.x;
    int w = t >> 6, lane = t & 63;
    int n = blockIdx.x * 4 + w;            // grid 2500
    int start = row_start[n], end = row_start[n + 1];
    int il = lane & (DIN - 1);
    int kh = lane / DIN;
    float s[KPL];
#pragma unroll
    for (int j = 0; j < KPL; j++) s[j] = 0.f;

    for (int p = start; p < end; p += 4) {
        int e1 = end - 1;
        int q0 = p;
        int q1 = (p + 1 < end) ? p + 1 : e1;
        int q2 = (p + 2 < end) ? p + 2 : e1;
        int q3 = (p + 3 < end) ? p + 3 : e1;
        bool v1 = p + 1 < end, v2 = p + 2 < end, v3 = p + 3 < end;
        int s0 = csr_src[q0], s1 = csr_src[q1], s2 = csr_src[q2], s3 = csr_src[q3];
        const float4* h0 = (const float4*)(hcsr + (size_t)q0 * 32 + kh * KPL);
        const float4* h1 = (const float4*)(hcsr + (size_t)q1 * 32 + kh * KPL);
        const float4* h2 = (const float4*)(hcsr + (size_t)q2 * 32 + kh * KPL);
        const float4* h3 = (const float4*)(hcsr + (size_t)q3 * 32 + kh * KPL);
        float4 H0[KPL / 4], H1[KPL / 4], H2[KPL / 4], H3[KPL / 4];
#pragma unroll
        for (int j4 = 0; j4 < KPL / 4; j4++) {
            H0[j4] = h0[j4]; H1[j4] = h1[j4]; H2[j4] = h2[j4]; H3[j4] = h3[j4];
        }
        float x0 = xin[s0 * DIN + il];
        float x1 = v1 ? xin[s1 * DIN + il] : 0.f;
        float x2 = v2 ? xin[s2 * DIN + il] : 0.f;
        float x3 = v3 ? xin[s3 * DIN + il] : 0.f;
#pragma unroll
        for (int j4 = 0; j4 < KPL / 4; j4++) {
            s[j4 * 4 + 0] += H0[j4].x * x0; s[j4 * 4 + 1] += H0[j4].y * x0;
            s[j4 * 4 + 2] += H0[j4].z * x0; s[j4 * 4 + 3] += H0[j4].w * x0;
        }
#pragma unroll
        for (int j4 = 0; j4 < KPL / 4; j4++) {
            s[j4 * 4 + 0] += H1[j4].x * x1; s[j4 * 4 + 1] += H1[j4].y * x1;
            s[j4 * 4 + 2] += H1[j4].z * x1; s[j4 * 4 + 3] += H1[j4].w * x1;
        }
#pragma unroll
        for (int j4 = 0; j4 < KPL / 4; j4++) {
            s[j4 * 4 + 0] += H2[j4].x * x2; s[j4 * 4 + 1] += H2[j4].y * x2;
            s[j4 * 4 + 2] += H2[j4].z * x2; s[j4 * 4 + 3] += H2[j4].w * x2;
        }
#pragma unroll
        for (int j4 = 0; j4 < KPL / 4; j4++) {
            s[j4 * 4 + 0] += H3[j4].x * x3; s[j4 * 4 + 1] += H3[j4].y * x3;
            s[j4 * 4 + 2] += H3[j4].z * x3; s[j4 * 4 + 3] += H3[j4].w * x3;
        }
    }
    float4* Sp = (float4*)(S + (size_t)n * KT + lane * KPL);
#pragma unroll
    for (int j4 = 0; j4 < KPL / 4; j4++) {
        float4 v; v.x = s[j4 * 4]; v.y = s[j4 * 4 + 1]; v.z = s[j4 * 4 + 2]; v.w = s[j4 * 4 + 3];
        Sp[j4] = v;
    }
}

// ---- Phase B: LDS-tiled GEMM out[16n x 32o] = S . W + epilogue.
// R12: BARRIER-FREE K-loop. Staging LDS is wave-private (Sl[w][..]) so no
// __syncthreads is needed inside the loop — within-wave LDS write->read
// ordering is enforced by compiler waitcnts. Double-buffered staging:
// chunk c+1 global loads issue while chunk c computes; L3 latency hides
// behind the 16-iter FMA body. Single barrier before cross-wave epilogue.
template <int DIN, int KT, bool FINAL>
__global__ void k_gemm(const float* __restrict__ S, const float* __restrict__ WT,
                       const int* __restrict__ row_start, const float* __restrict__ xin,
                       const float* __restrict__ wr, const float* __restrict__ bc,
                       const int* __restrict__ batch, float* __restrict__ xout,
                       float* __restrict__ gsum) {
    __shared__ __align__(16) float Sl[4][2][16][68];  // wave-private, dbuf
    __shared__ __align__(16) float redf[4][16][36];   // cross-wave partials
    int t = threadIdx.x;
    int w = t >> 6, lane = t & 63;
    int nb = blockIdx.x * 16;              // grid 625 exact
    int ng = lane >> 3, og = lane & 7;     // 8 n-groups x 8 o-groups
    int n0 = ng * 2, n1 = n0 + 1;
    const int KW = KT / 4;                 // per-wave K range (256 / 128)
    const int NC = KW / 64;                // chunks (4 / 2)
    int kbase = w * KW;
    float a0 = 0.f, a1 = 0.f, a2 = 0.f, a3 = 0.f;
    float b0 = 0.f, b1 = 0.f, b2 = 0.f, b3 = 0.f;
    int sn = lane >> 2, kq = lane & 3;     // staging map: 16 n x 4 k-quarters
    const float* Sbase = S + (size_t)(nb + sn) * KT + kbase + kq * 16;
    // prologue: chunk 0 into registers
    float4 r0 = ((const float4*)Sbase)[0];
    float4 r1 = ((const float4*)Sbase)[1];
    float4 r2 = ((const float4*)Sbase)[2];
    float4 r3 = ((const float4*)Sbase)[3];
    for (int c = 0; c < NC; c++) {
        int buf = c & 1;
        float4* lsd = (float4*)&Sl[w][buf][sn][kq * 16];
        lsd[0] = r0; lsd[1] = r1; lsd[2] = r2; lsd[3] = r3;
        if (c + 1 < NC) {
            const float4* gn = (const float4*)(Sbase + (c + 1) * 64);
            r0 = gn[0]; r1 = gn[1]; r2 = gn[2]; r3 = gn[3];
        }
        const float* wp0 = WT + (size_t)(kbase + c * 64) * 32 + og * 4;
#pragma unroll 8
        for (int kk = 0; kk < 64; kk += 4) {
            float4 s0 = *(const float4*)&Sl[w][buf][n0][kk];
            float4 s1 = *(const float4*)&Sl[w][buf][n1][kk];
            const float* wp = wp0 + kk * 32;
            float4 w0 = *(const float4*)(wp);
            float4 w1 = *(const float4*)(wp + 32);
            float4 w2 = *(const float4*)(wp + 64);
            float4 w3 = *(const float4*)(wp + 96);
            a0 += s0.x * w0.x + s0.y * w1.x + s0.z * w2.x + s0.w * w3.x;
            a1 += s0.x * w0.y + s0.y * w1.y + s0.z * w2.y + s0.w * w3.y;
            a2 += s0.x * w0.z + s0.y * w1.z + s0.z * w2.z + s0.w * w3.z;
            a3 += s0.x * w0.w + s0.y * w1.w + s0.z * w2.w + s0.w * w3.w;
            b0 += s1.x * w0.x + s1.y * w1.x + s1.z * w2.x + s1.w * w3.x;
            b1 += s1.x * w0.y + s1.y * w1.y + s1.z * w2.y + s1.w * w3.y;
            b2 += s1.x * w0.z + s1.y * w1.z + s1.z * w2.z + s1.w * w3.z;
            b3 += s1.x * w0.w + s1.y * w1.w + s1.z * w2.w + s1.w * w3.w;
        }
    }
    float4 va; va.x = a0; va.y = a1; va.z = a2; va.w = a3;
    float4 vb; vb.x = b0; vb.y = b1; vb.z = b2; vb.w = b3;
    *(float4*)&redf[w][n0][og * 4] = va;
    *(float4*)&redf[w][n1][og * 4] = vb;
    __syncthreads();
    if (t >= 128) return;
    // ---- epilogue: 128 threads = 16 nodes x 8 o-quads ----
    int nl = t >> 3, og2 = t & 7, ob = og2 * 4;
    int n = nb + nl;
    float4 p0 = *(const float4*)&redf[0][nl][ob];
    float4 p1 = *(const float4*)&redf[1][nl][ob];
    float4 p2 = *(const float4*)&redf[2][nl][ob];
    float4 p3 = *(const float4*)&redf[3][nl][ob];
    float r0e = p0.x + p1.x + p2.x + p3.x;
    float r1e = p0.y + p1.y + p2.y + p3.y;
    float r2e = p0.z + p1.z + p2.z + p3.z;
    float r3e = p0.w + p1.w + p2.w + p3.w;
    int cnt = row_start[n + 1] - row_start[n];
    float d = (float)cnt; if (d < 1.f) d = 1.f;
    float4 bcv = *(const float4*)(bc + ob);
    r0e = r0e / d + bcv.x; r1e = r1e / d + bcv.y; r2e = r2e / d + bcv.z; r3e = r3e / d + bcv.w;
    const float4* xr = (const float4*)(xin + (size_t)n * DIN);
#pragma unroll
    for (int i4 = 0; i4 < DIN / 4; i4++) {
        float4 xv = xr[i4];
        float4 wv0 = *(const float4*)(wr + (i4 * 4 + 0) * DOUT + ob);
        float4 wv1 = *(const float4*)(wr + (i4 * 4 + 1) * DOUT + ob);
        float4 wv2 = *(const float4*)(wr + (i4 * 4 + 2) * DOUT + ob);
        float4 wv3 = *(const float4*)(wr + (i4 * 4 + 3) * DOUT + ob);
        r0e += xv.x * wv0.x + xv.y * wv1.x + xv.z * wv2.x + xv.w * wv3.x;
        r1e += xv.x * wv0.y + xv.y * wv1.y + xv.z * wv2.y + xv.w * wv3.y;
        r2e += xv.x * wv0.z + xv.y * wv1.z + xv.z * wv2.z + xv.w * wv3.z;
        r3e += xv.x * wv0.w + xv.y * wv1.w + xv.z * wv2.w + xv.w * wv3.w;
    }
    r0e = r0e > 0.f ? r0e : expm1f(r0e);
    r1e = r1e > 0.f ? r1e : expm1f(r1e);
    r2e = r2e > 0.f ? r2e : expm1f(r2e);
    r3e = r3e > 0.f ? r3e : expm1f(r3e);
    if (FINAL) {
        int b = batch[n];
        atomicAdd(gsum + b * DOUT + ob + 0, r0e);
        atomicAdd(gsum + b * DOUT + ob + 1, r1e);
        atomicAdd(gsum + b * DOUT + ob + 2, r2e);
        atomicAdd(gsum + b * DOUT + ob + 3, r3e);
    } else {
        xout[n * DOUT + ob + 0] = r0e;
        xout[n * DOUT + ob + 1] = r1e;
        xout[n * DOUT + ob + 2] = r2e;
        xout[n * DOUT + ob + 3] = r3e;
    }
}

// ---- final fc; per-graph node counts via binary search on SORTED batch
__global__ void k_fc(const float* __restrict__ gsum, const int* __restrict__ batch,
                     const float* __restrict__ wfc, const float* __restrict__ bfc,
                     float* __restrict__ out) {
    int g = threadIdx.x;
    if (g >= GG) return;
    int lo = 0, hi = NN;
    while (lo < hi) { int mid = (lo + hi) >> 1; if (batch[mid] < g) lo = mid + 1; else hi = mid; }
    int lb = lo;
    lo = 0; hi = NN;
    while (lo < hi) { int mid = (lo + hi) >> 1; if (batch[mid] < g + 1) lo = mid + 1; else hi = mid; }
    float c = (float)(lo - lb); if (c < 1.f) c = 1.f;
    float acc = 0.f;
#pragma unroll
    for (int o = 0; o < DOUT; o++) acc += gsum[g * DOUT + o] * wfc[o];
    out[g] = acc / c + bfc[0];
}

extern "C" void kernel_launch(void* const* d_in, const int* in_sizes, int n_in,
                              void* d_out, int out_size, void* d_ws, size_t ws_size,
                              hipStream_t stream) {
    const float* x     = (const float*)d_in[0];
    const float* ea    = (const float*)d_in[1];
    const int*   ei    = (const int*)d_in[2];
    const int*   batch = (const int*)d_in[3];
    const float* w1_0 = (const float*)d_in[4];
    const float* b1_0 = (const float*)d_in[5];
    const float* g_0  = (const float*)d_in[6];
    const float* be_0 = (const float*)d_in[7];
    const float* w2_0 = (const float*)d_in[8];
    const float* b2_0 = (const float*)d_in[9];
    const float* wr_0 = (const float*)d_in[10];
    const float* bc_0 = (const float*)d_in[11];
    const float* w1_1 = (const float*)d_in[12];
    const float* b1_1 = (const float*)d_in[13];
    const float* g_1  = (const float*)d_in[14];
    const float* be_1 = (const float*)d_in[15];
    const float* w2_1 = (const float*)d_in[16];
    const float* b2_1 = (const float*)d_in[17];
    const float* wr_1 = (const float*)d_in[18];
    const float* bc_1 = (const float*)d_in[19];
    const float* wfc  = (const float*)d_in[20];
    const float* bfc  = (const float*)d_in[21];

    float* ws    = (float*)d_ws;
    int*   cur   = (int*)(ws + OFF_CUR);
    float* gsum  = ws + OFF_GSUM;
    int*   degc  = (int*)(ws + OFF_DEGC);
    float* mop   = ws + OFF_MOP;
    float* w1f0  = ws + OFF_W1F0;
    float* b1f0  = ws + OFF_B1F0;
    float* w1f1  = ws + OFF_W1F1;
    float* b1f1  = ws + OFF_B1F1;
    int*   row   = (int*)(ws + OFF_ROW);
    int*   csrc  = (int*)(ws + OFF_SRC);
    int*   ceid  = (int*)(ws + OFF_EID);
    float* wt0   = ws + OFF_WT0;
    float* wt1   = ws + OFF_WT1;
    float* hcsr  = ws + OFF_H;
    float* Sbuf  = ws + OFF_S;
    float* x1    = ws + OFF_X1;

    hipMemsetAsync(ws, 0, (size_t)ZERO_FLOATS * sizeof(float), stream);

    k_momdeg<<<64, 256, 0, stream>>>(ea, ei, mop, degc);
    k_scan<<<1, 256, 0, stream>>>(degc, row);
    k_scatter<<<(EE + 255) / 256, 256, 0, stream>>>(ei, row, cur, csrc, ceid);
    k_prep<<<193, 256, 0, stream>>>(mop, w1_0, b1_0, g_0, be_0, w1_1, b1_1, g_1, be_1,
                                    w2_0, b2_0, w2_1, b2_1,
                                    w1f0, b1f0, w1f1, b1f1, wt0, wt1);

    // ---- layer 0 (din=16, K=512)
    k_h<<<EE / 8, 256, 0, stream>>>(ea, ceid, w1f0, b1f0, hcsr);
    k_sedge<16, 8, 512><<<NN / 4, 256, 0, stream>>>(row, csrc, hcsr, x, Sbuf);
    k_gemm<16, 512, false><<<NN / 16, 256, 0, stream>>>(Sbuf, wt0, row, x, wr_0, bc_0,
                                                        batch, x1, gsum);

    // ---- layer 1 (din=32, K=1024), pool fused into epilogue
    k_h<<<EE / 8, 256, 0, stream>>>(ea, ceid, w1f1, b1f1, hcsr);
    k_sedge<32, 16, 1024><<<NN / 4, 256, 0, stream>>>(row, csrc, hcsr, x1, Sbuf);
    k_gemm<32, 1024, true><<<NN / 16, 256, 0, stream>>>(Sbuf, wt1, row, x1, wr_1, bc_1,
                                                        batch, nullptr, gsum);

    // ---- fc (counts via binary search on sorted batch)
    k_fc<<<1, 128, 0, stream>>>(gsum, batch, wfc, bfc, (float*)d_out);
}

// Round 13
// 300.911 us; speedup vs baseline: 1.5080x; 1.0040x over previous
//
#include <hip/hip_runtime.h>
#include <math.h>

// Problem constants (fixed by reference)
#define NN   10000
#define EE   160000
#define GG   128
#define HIDK 25
#define DOUT 32
#define EPSBN 1e-5f

// ---------------- workspace layout (float offsets) ----------------
// zeroed region (one hipMemsetAsync):
#define OFF_CUR   0          // NN ints (scatter cursors), pad 10016
#define OFF_GSUM  10016      // G*32 = 4096
#define OFF_DEGC  14112      // NN ints, pad 10016
#define ZERO_FLOATS 24128
// non-zeroed:
#define OFF_MOP   24128      // 64*12
#define OFF_W1F0  24896      // 80
#define OFF_B1F0  24976      // 32
#define OFF_W1F1  25008      // 80
#define OFF_B1F1  25088      // 32
#define OFF_ROW   25120      // NN+1 ints, pad 10016
#define OFF_SRC   35136      // E ints
#define OFF_EID   195136     // E ints
#define OFF_WT0   355136     // 512*32  = 16384  (W[K][o], layer0)
#define OFF_WT1   371520     // 1024*32 = 32768  (W[K][o], layer1)
#define OFF_H     404288     // E*32 = 5,120,000 (h in CSR-slot order, per layer)
#define OFF_S     5524288    // N*1024 = 10,240,000 (S, shared by both layers)
#define OFF_X1    15764288   // N*32
#define TOTAL_FLOATS 16084288 // ~64.3 MB of d_ws

__device__ inline float wave_red(float v) {
    for (int off = 32; off; off >>= 1) v += __shfl_down(v, off);
    return v;
}

// ---- moments partials (64 blocks, atomic-free) + in-degree atomics, one pass
__global__ void k_momdeg(const float* __restrict__ ea, const int* __restrict__ ei,
                         float* __restrict__ mop, int* __restrict__ degc) {
    __shared__ float ls[4][9];
    float s[9];
#pragma unroll
    for (int j = 0; j < 9; j++) s[j] = 0.f;
    int t = threadIdx.x;
    for (int e = blockIdx.x * 256 + t; e < EE; e += 64 * 256) {
        float a0 = ea[3 * e], a1 = ea[3 * e + 1], a2 = ea[3 * e + 2];
        s[0] += a0; s[1] += a1; s[2] += a2;
        s[3] += a0 * a0; s[4] += a0 * a1; s[5] += a0 * a2;
        s[6] += a1 * a1; s[7] += a1 * a2; s[8] += a2 * a2;
        atomicAdd(degc + ei[EE + e], 1);
    }
    int w = t >> 6, lane = t & 63;
#pragma unroll
    for (int j = 0; j < 9; j++) {
        float r = wave_red(s[j]);
        if (lane == 0) ls[w][j] = r;
    }
    __syncthreads();
    if (t < 9) mop[blockIdx.x * 12 + t] = ls[0][t] + ls[1][t] + ls[2][t] + ls[3][t];
}

// ---- single-block exclusive scan of degc -> row_start[NN+1]
__global__ void k_scan(const int* __restrict__ degc, int* __restrict__ row_start) {
    __shared__ int p[256];
    int t = threadIdx.x;
    const int CHUNK = 40;                 // 250*40 == 10000 exactly
    int base = t * CHUNK;
    int sum = 0;
    if (t < 250) {
        for (int i = 0; i < CHUNK; i++) sum += degc[base + i];
    }
    p[t] = sum;
    __syncthreads();
    for (int off = 1; off < 256; off <<= 1) {
        int v = (t >= off) ? p[t - off] : 0;
        __syncthreads();
        p[t] += v;
        __syncthreads();
    }
    int excl = p[t] - sum;
    if (t < 250) {
        int run = excl;
        for (int i = 0; i < CHUNK; i++) {
            row_start[base + i] = run;
            run += degc[base + i];
        }
    }
    if (t == 0) row_start[NN] = EE;
}

// ---- scatter edges into CSR slots
__global__ void k_scatter(const int* __restrict__ ei, const int* __restrict__ row_start,
                          int* __restrict__ cur, int* __restrict__ csr_src,
                          int* __restrict__ csr_eid) {
    int e = blockIdx.x * blockDim.x + threadIdx.x;
    if (e >= EE) return;
    int d = ei[EE + e];
    int pos = atomicAdd(cur + d, 1);
    int idx = row_start[d] + pos;
    csr_src[idx] = ei[e];
    csr_eid[idx] = e;
}

// ---- merged prep: blocks 0..191 pack W[K][o] for both layers; block 192 folds BN.
// K is the S-layout index from k_sedge: K = lane*KPL + j, lane = (kh,il):
//   il = lane & (DIN-1), kh = lane / DIN, k = kh*KPL + j.
// k<25 -> w2[k][il][o] ; k==25 -> b2[il][o] ; k>25 -> 0.
__global__ void k_prep(const float* __restrict__ mop,
                       const float* __restrict__ w1_0, const float* __restrict__ b1_0,
                       const float* __restrict__ g_0, const float* __restrict__ be_0,
                       const float* __restrict__ w1_1, const float* __restrict__ b1_1,
                       const float* __restrict__ g_1, const float* __restrict__ be_1,
                       const float* __restrict__ w2_0, const float* __restrict__ b2_0,
                       const float* __restrict__ w2_1, const float* __restrict__ b2_1,
                       float* __restrict__ w1f0, float* __restrict__ b1f0,
                       float* __restrict__ w1f1, float* __restrict__ b1f1,
                       float* __restrict__ wt0, float* __restrict__ wt1) {
    int b = blockIdx.x, t = threadIdx.x;
    if (b < 192) {
        int idx = b * 256 + t;
        if (idx < 512 * 32) {                       // layer0: KT=512, DIN=16, KPL=8
            int K = idx >> 5, o = idx & 31;
            int lane = K >> 3, j = K & 7;
            int kh = lane >> 4, il = lane & 15;
            int k = kh * 8 + j;
            float v = 0.f;
            if (k < HIDK) v = w2_0[(k * 16 + il) * DOUT + o];
            else if (k == HIDK) v = b2_0[il * DOUT + o];
            wt0[idx] = v;
        } else {                                    // layer1: KT=1024, DIN=32, KPL=16
            int idx2 = idx - 512 * 32;
            int K = idx2 >> 5, o = idx2 & 31;
            int lane = K >> 4, j = K & 15;
            int kh = lane >> 5, il = lane & 31;
            int k = kh * 16 + j;
            float v = 0.f;
            if (k < HIDK) v = w2_1[(k * 32 + il) * DOUT + o];
            else if (k == HIDK) v = b2_1[il * DOUT + o];
            wt1[idx2] = v;
        }
        return;
    }
    // ---- block 192: fold BN for both layers
    __shared__ float mo[9];
    if (t < 9) {
        float s = 0.f;
        for (int bb = 0; bb < 64; bb++) s += mop[bb * 12 + t];
        mo[t] = s;
    }
    __syncthreads();
    int grp = t >> 5, j = t & 31;
    if (t >= 64 || j >= HIDK) return;
    const float* w1 = grp ? w1_1 : w1_0;
    const float* b1 = grp ? b1_1 : b1_0;
    const float* g  = grp ? g_1  : g_0;
    const float* be = grp ? be_1 : be_0;
    float* w1f = grp ? w1f1 : w1f0;
    float* b1f = grp ? b1f1 : b1f0;
    const float inv = 1.0f / (float)EE;
    float m0 = mo[0] * inv, m1 = mo[1] * inv, m2 = mo[2] * inv;
    float c00 = mo[3] * inv - m0 * m0, c01 = mo[4] * inv - m0 * m1, c02 = mo[5] * inv - m0 * m2;
    float c11 = mo[6] * inv - m1 * m1, c12 = mo[7] * inv - m1 * m2, c22 = mo[8] * inv - m2 * m2;
    float w0 = w1[j], wa = w1[25 + j], wb = w1[50 + j];
    float mean = m0 * w0 + m1 * wa + m2 * wb + b1[j];
    float var = w0 * w0 * c00 + wa * wa * c11 + wb * wb * c22
              + 2.f * (w0 * wa * c01 + w0 * wb * c02 + wa * wb * c12);
    float sc = g[j] * rsqrtf(var + EPSBN);
    w1f[j] = w0 * sc; w1f[25 + j] = wa * sc; w1f[50 + j] = wb * sc;
    b1f[j] = (b1[j] - mean) * sc + be[j];
}

// ---- h in CSR-slot order: hcsr[slot][k] = relu(ea[eid]@w1f+b1f)[k]; k=25 -> 1; pad -> 0
__global__ void k_h(const float* __restrict__ ea, const int* __restrict__ csr_eid,
                    const float* __restrict__ w1f, const float* __restrict__ b1f,
                    float* __restrict__ hcsr) {
    int t = threadIdx.x;
    int slot = blockIdx.x * 8 + (t >> 5);   // 20000 blocks exactly
    int k = t & 31;
    int e = csr_eid[slot];
    float v = 0.f;
    if (k < HIDK) {
        float a0 = ea[3 * e], a1 = ea[3 * e + 1], a2 = ea[3 * e + 2];
        v = a0 * w1f[k] + a1 * w1f[25 + k] + a2 * w1f[50 + k] + b1f[k];
        v = v > 0.f ? v : 0.f;
    } else if (k == HIDK) {
        v = 1.0f;
    }
    hcsr[(size_t)slot * 32 + k] = v;
}

// ---- Phase A: S[n][K] = sum_{edges of n} h[slot][k] * x[src, i]
// One wave per node, 4-edge unroll, S in registers, no LDS/barriers.
// Lane layout: il = lane & (DIN-1), kh = lane/DIN owns k = kh*KPL + j.
// S stored lane-major: S[n*KT + lane*KPL + j] -> KPL/4 coalesced b128 stores.
// R13: __launch_bounds__(256,3) — the default 64-VGPR budget serialized the
// 4-edge unroll's H loads (s[16] + 16 H-float4 ≈ 100 live regs needed).
template <int DIN, int KPL, int KT>
__launch_bounds__(256, 3)
__global__ void k_sedge(const int* __restrict__ row_start, const int* __restrict__ csr_src,
                        const float* __restrict__ hcsr, const float* __restrict__ xin,
                        float* __restrict__ S) {
    int t = threadIdx.x;
    int w = t >> 6, lane = t & 63;
    int n = blockIdx.x * 4 + w;            // grid 2500
    int start = row_start[n], end = row_start[n + 1];
    int il = lane & (DIN - 1);
    int kh = lane / DIN;
    float s[KPL];
#pragma unroll
    for (int j = 0; j < KPL; j++) s[j] = 0.f;

    for (int p = start; p < end; p += 4) {
        int e1 = end - 1;
        int q0 = p;
        int q1 = (p + 1 < end) ? p + 1 : e1;
        int q2 = (p + 2 < end) ? p + 2 : e1;
        int q3 = (p + 3 < end) ? p + 3 : e1;
        bool v1 = p + 1 < end, v2 = p + 2 < end, v3 = p + 3 < end;
        int s0 = csr_src[q0], s1 = csr_src[q1], s2 = csr_src[q2], s3 = csr_src[q3];
        const float4* h0 = (const float4*)(hcsr + (size_t)q0 * 32 + kh * KPL);
        const float4* h1 = (const float4*)(hcsr + (size_t)q1 * 32 + kh * KPL);
        const float4* h2 = (const float4*)(hcsr + (size_t)q2 * 32 + kh * KPL);
        const float4* h3 = (const float4*)(hcsr + (size_t)q3 * 32 + kh * KPL);
        float4 H0[KPL / 4], H1[KPL / 4], H2[KPL / 4], H3[KPL / 4];
#pragma unroll
        for (int j4 = 0; j4 < KPL / 4; j4++) {
            H0[j4] = h0[j4]; H1[j4] = h1[j4]; H2[j4] = h2[j4]; H3[j4] = h3[j4];
        }
        float x0 = xin[s0 * DIN + il];
        float x1 = v1 ? xin[s1 * DIN + il] : 0.f;
        float x2 = v2 ? xin[s2 * DIN + il] : 0.f;
        float x3 = v3 ? xin[s3 * DIN + il] : 0.f;
#pragma unroll
        for (int j4 = 0; j4 < KPL / 4; j4++) {
            s[j4 * 4 + 0] += H0[j4].x * x0; s[j4 * 4 + 1] += H0[j4].y * x0;
            s[j4 * 4 + 2] += H0[j4].z * x0; s[j4 * 4 + 3] += H0[j4].w * x0;
        }
#pragma unroll
        for (int j4 = 0; j4 < KPL / 4; j4++) {
            s[j4 * 4 + 0] += H1[j4].x * x1; s[j4 * 4 + 1] += H1[j4].y * x1;
            s[j4 * 4 + 2] += H1[j4].z * x1; s[j4 * 4 + 3] += H1[j4].w * x1;
        }
#pragma unroll
        for (int j4 = 0; j4 < KPL / 4; j4++) {
            s[j4 * 4 + 0] += H2[j4].x * x2; s[j4 * 4 + 1] += H2[j4].y * x2;
            s[j4 * 4 + 2] += H2[j4].z * x2; s[j4 * 4 + 3] += H2[j4].w * x2;
        }
#pragma unroll
        for (int j4 = 0; j4 < KPL / 4; j4++) {
            s[j4 * 4 + 0] += H3[j4].x * x3; s[j4 * 4 + 1] += H3[j4].y * x3;
            s[j4 * 4 + 2] += H3[j4].z * x3; s[j4 * 4 + 3] += H3[j4].w * x3;
        }
    }
    float4* Sp = (float4*)(S + (size_t)n * KT + lane * KPL);
#pragma unroll
    for (int j4 = 0; j4 < KPL / 4; j4++) {
        float4 v; v.x = s[j4 * 4]; v.y = s[j4 * 4 + 1]; v.z = s[j4 * 4 + 2]; v.w = s[j4 * 4 + 3];
        Sp[j4] = v;
    }
}

// ---- Phase B: LDS-tiled GEMM out[16n x 32o] = S . W + epilogue.
// R13: __launch_bounds__(256,2) — R10-R12 all ran at the allocator's default
// 64-VGPR budget, which serialized every load (per-block time ~65k cycles =
// 1000 cyc/iter = 6 serialized ~170-cyc loads; VALUBusy 9%). 256-VGPR budget
// lets the 8-deep unroll keep ~24 float4 loads in flight. Barrier-free
// wave-private staging (dbuf) retained from R12.
template <int DIN, int KT, bool FINAL>
__launch_bounds__(256, 2)
__global__ void k_gemm(const float* __restrict__ S, const float* __restrict__ WT,
                       const int* __restrict__ row_start, const float* __restrict__ xin,
                       const float* __restrict__ wr, const float* __restrict__ bc,
                       const int* __restrict__ batch, float* __restrict__ xout,
                       float* __restrict__ gsum) {
    __shared__ __align__(16) float Sl[4][2][16][68];  // wave-private, dbuf
    __shared__ __align__(16) float redf[4][16][36];   // cross-wave partials
    int t = threadIdx.x;
    int w = t >> 6, lane = t & 63;
    int nb = blockIdx.x * 16;              // grid 625 exact
    int ng = lane >> 3, og = lane & 7;     // 8 n-groups x 8 o-groups
    int n0 = ng * 2, n1 = n0 + 1;
    const int KW = KT / 4;                 // per-wave K range (256 / 128)
    const int NC = KW / 64;                // chunks (4 / 2)
    int kbase = w * KW;
    float a0 = 0.f, a1 = 0.f, a2 = 0.f, a3 = 0.f;
    float b0 = 0.f, b1 = 0.f, b2 = 0.f, b3 = 0.f;
    int sn = lane >> 2, kq = lane & 3;     // staging map: 16 n x 4 k-quarters
    const float* Sbase = S + (size_t)(nb + sn) * KT + kbase + kq * 16;
    // prologue: chunk 0 into registers
    float4 r0 = ((const float4*)Sbase)[0];
    float4 r1 = ((const float4*)Sbase)[1];
    float4 r2 = ((const float4*)Sbase)[2];
    float4 r3 = ((const float4*)Sbase)[3];
    for (int c = 0; c < NC; c++) {
        int buf = c & 1;
        float4* lsd = (float4*)&Sl[w][buf][sn][kq * 16];
        lsd[0] = r0; lsd[1] = r1; lsd[2] = r2; lsd[3] = r3;
        if (c + 1 < NC) {
            const float4* gn = (const float4*)(Sbase + (c + 1) * 64);
            r0 = gn[0]; r1 = gn[1]; r2 = gn[2]; r3 = gn[3];
        }
        const float* wp0 = WT + (size_t)(kbase + c * 64) * 32 + og * 4;
#pragma unroll 8
        for (int kk = 0; kk < 64; kk += 4) {
            float4 s0 = *(const float4*)&Sl[w][buf][n0][kk];
            float4 s1 = *(const float4*)&Sl[w][buf][n1][kk];
            const float* wp = wp0 + kk * 32;
            float4 w0 = *(const float4*)(wp);
            float4 w1 = *(const float4*)(wp + 32);
            float4 w2 = *(const float4*)(wp + 64);
            float4 w3 = *(const float4*)(wp + 96);
            a0 += s0.x * w0.x + s0.y * w1.x + s0.z * w2.x + s0.w * w3.x;
            a1 += s0.x * w0.y + s0.y * w1.y + s0.z * w2.y + s0.w * w3.y;
            a2 += s0.x * w0.z + s0.y * w1.z + s0.z * w2.z + s0.w * w3.z;
            a3 += s0.x * w0.w + s0.y * w1.w + s0.z * w2.w + s0.w * w3.w;
            b0 += s1.x * w0.x + s1.y * w1.x + s1.z * w2.x + s1.w * w3.x;
            b1 += s1.x * w0.y + s1.y * w1.y + s1.z * w2.y + s1.w * w3.y;
            b2 += s1.x * w0.z + s1.y * w1.z + s1.z * w2.z + s1.w * w3.z;
            b3 += s1.x * w0.w + s1.y * w1.w + s1.z * w2.w + s1.w * w3.w;
        }
    }
    float4 va; va.x = a0; va.y = a1; va.z = a2; va.w = a3;
    float4 vb; vb.x = b0; vb.y = b1; vb.z = b2; vb.w = b3;
    *(float4*)&redf[w][n0][og * 4] = va;
    *(float4*)&redf[w][n1][og * 4] = vb;
    __syncthreads();
    if (t >= 128) return;
    // ---- epilogue: 128 threads = 16 nodes x 8 o-quads ----
    int nl = t >> 3, og2 = t & 7, ob = og2 * 4;
    int n = nb + nl;
    float4 p0 = *(const float4*)&redf[0][nl][ob];
    float4 p1 = *(const float4*)&redf[1][nl][ob];
    float4 p2 = *(const float4*)&redf[2][nl][ob];
    float4 p3 = *(const float4*)&redf[3][nl][ob];
    float r0e = p0.x + p1.x + p2.x + p3.x;
    float r1e = p0.y + p1.y + p2.y + p3.y;
    float r2e = p0.z + p1.z + p2.z + p3.z;
    float r3e = p0.w + p1.w + p2.w + p3.w;
    int cnt = row_start[n + 1] - row_start[n];
    float d = (float)cnt; if (d < 1.f) d = 1.f;
    float4 bcv = *(const float4*)(bc + ob);
    r0e = r0e / d + bcv.x; r1e = r1e / d + bcv.y; r2e = r2e / d + bcv.z; r3e = r3e / d + bcv.w;
    const float4* xr = (const float4*)(xin + (size_t)n * DIN);
#pragma unroll
    for (int i4 = 0; i4 < DIN / 4; i4++) {
        float4 xv = xr[i4];
        float4 wv0 = *(const float4*)(wr + (i4 * 4 + 0) * DOUT + ob);
        float4 wv1 = *(const float4*)(wr + (i4 * 4 + 1) * DOUT + ob);
        float4 wv2 = *(const float4*)(wr + (i4 * 4 + 2) * DOUT + ob);
        float4 wv3 = *(const float4*)(wr + (i4 * 4 + 3) * DOUT + ob);
        r0e += xv.x * wv0.x + xv.y * wv1.x + xv.z * wv2.x + xv.w * wv3.x;
        r1e += xv.x * wv0.y + xv.y * wv1.y + xv.z * wv2.y + xv.w * wv3.y;
        r2e += xv.x * wv0.z + xv.y * wv1.z + xv.z * wv2.z + xv.w * wv3.z;
        r3e += xv.x * wv0.w + xv.y * wv1.w + xv.z * wv2.w + xv.w * wv3.w;
    }
    r0e = r0e > 0.f ? r0e : expm1f(r0e);
    r1e = r1e > 0.f ? r1e : expm1f(r1e);
    r2e = r2e > 0.f ? r2e : expm1f(r2e);
    r3e = r3e > 0.f ? r3e : expm1f(r3e);
    if (FINAL) {
        int b = batch[n];
        atomicAdd(gsum + b * DOUT + ob + 0, r0e);
        atomicAdd(gsum + b * DOUT + ob + 1, r1e);
        atomicAdd(gsum + b * DOUT + ob + 2, r2e);
        atomicAdd(gsum + b * DOUT + ob + 3, r3e);
    } else {
        xout[n * DOUT + ob + 0] = r0e;
        xout[n * DOUT + ob + 1] = r1e;
        xout[n * DOUT + ob + 2] = r2e;
        xout[n * DOUT + ob + 3] = r3e;
    }
}

// ---- final fc; per-graph node counts via binary search on SORTED batch
__global__ void k_fc(const float* __restrict__ gsum, const int* __restrict__ batch,
                     const float* __restrict__ wfc, const float* __restrict__ bfc,
                     float* __restrict__ out) {
    int g = threadIdx.x;
    if (g >= GG) return;
    int lo = 0, hi = NN;
    while (lo < hi) { int mid = (lo + hi) >> 1; if (batch[mid] < g) lo = mid + 1; else hi = mid; }
    int lb = lo;
    lo = 0; hi = NN;
    while (lo < hi) { int mid = (lo + hi) >> 1; if (batch[mid] < g + 1) lo = mid + 1; else hi = mid; }
    float c = (float)(lo - lb); if (c < 1.f) c = 1.f;
    float acc = 0.f;
#pragma unroll
    for (int o = 0; o < DOUT; o++) acc += gsum[g * DOUT + o] * wfc[o];
    out[g] = acc / c + bfc[0];
}

extern "C" void kernel_launch(void* const* d_in, const int* in_sizes, int n_in,
                              void* d_out, int out_size, void* d_ws, size_t ws_size,
                              hipStream_t stream) {
    const float* x     = (const float*)d_in[0];
    const float* ea    = (const float*)d_in[1];
    const int*   ei    = (const int*)d_in[2];
    const int*   batch = (const int*)d_in[3];
    const float* w1_0 = (const float*)d_in[4];
    const float* b1_0 = (const float*)d_in[5];
    const float* g_0  = (const float*)d_in[6];
    const float* be_0 = (const float*)d_in[7];
    const float* w2_0 = (const float*)d_in[8];
    const float* b2_0 = (const float*)d_in[9];
    const float* wr_0 = (const float*)d_in[10];
    const float* bc_0 = (const float*)d_in[11];
    const float* w1_1 = (const float*)d_in[12];
    const float* b1_1 = (const float*)d_in[13];
    const float* g_1  = (const float*)d_in[14];
    const float* be_1 = (const float*)d_in[15];
    const float* w2_1 = (const float*)d_in[16];
    const float* b2_1 = (const float*)d_in[17];
    const float* wr_1 = (const float*)d_in[18];
    const float* bc_1 = (const float*)d_in[19];
    const float* wfc  = (const float*)d_in[20];
    const float* bfc  = (const float*)d_in[21];

    float* ws    = (float*)d_ws;
    int*   cur   = (int*)(ws + OFF_CUR);
    float* gsum  = ws + OFF_GSUM;
    int*   degc  = (int*)(ws + OFF_DEGC);
    float* mop   = ws + OFF_MOP;
    float* w1f0  = ws + OFF_W1F0;
    float* b1f0  = ws + OFF_B1F0;
    float* w1f1  = ws + OFF_W1F1;
    float* b1f1  = ws + OFF_B1F1;
    int*   row   = (int*)(ws + OFF_ROW);
    int*   csrc  = (int*)(ws + OFF_SRC);
    int*   ceid  = (int*)(ws + OFF_EID);
    float* wt0   = ws + OFF_WT0;
    float* wt1   = ws + OFF_WT1;
    float* hcsr  = ws + OFF_H;
    float* Sbuf  = ws + OFF_S;
    float* x1    = ws + OFF_X1;

    hipMemsetAsync(ws, 0, (size_t)ZERO_FLOATS * sizeof(float), stream);

    k_momdeg<<<64, 256, 0, stream>>>(ea, ei, mop, degc);
    k_scan<<<1, 256, 0, stream>>>(degc, row);
    k_scatter<<<(EE + 255) / 256, 256, 0, stream>>>(ei, row, cur, csrc, ceid);
    k_prep<<<193, 256, 0, stream>>>(mop, w1_0, b1_0, g_0, be_0, w1_1, b1_1, g_1, be_1,
                                    w2_0, b2_0, w2_1, b2_1,
                                    w1f0, b1f0, w1f1, b1f1, wt0, wt1);

    // ---- layer 0 (din=16, K=512)
    k_h<<<EE / 8, 256, 0, stream>>>(ea, ceid, w1f0, b1f0, hcsr);
    k_sedge<16, 8, 512><<<NN / 4, 256, 0, stream>>>(row, csrc, hcsr, x, Sbuf);
    k_gemm<16, 512, false><<<NN / 16, 256, 0, stream>>>(Sbuf, wt0, row, x, wr_0, bc_0,
                                                        batch, x1, gsum);

    // ---- layer 1 (din=32, K=1024), pool fused into epilogue
    k_h<<<EE / 8, 256, 0, stream>>>(ea, ceid, w1f1, b1f1, hcsr);
    k_sedge<32, 16, 1024><<<NN / 4, 256, 0, stream>>>(row, csrc, hcsr, x1, Sbuf);
    k_gemm<32, 1024, true><<<NN / 16, 256, 0, stream>>>(Sbuf, wt1, row, x1, wr_1, bc_1,
                                                        batch, nullptr, gsum);

    // ---- fc (counts via binary search on sorted batch)
    k_fc<<<1, 128, 0, stream>>>(gsum, batch, wfc, bfc, (float*)d_out);
}